// Round 11
// baseline (988.144 us; speedup 1.0000x reference)
//
#include <hip/hip_runtime.h>
#include <cstdint>
#include <cstddef>

// ---------------- constants ----------------
#define DM   1024          // model dim
#define NT   8192          // B*L tokens
#define HD   256
#define BM 128
#define BN 128
#define BK 64

typedef __attribute__((ext_vector_type(4))) float f32x4;
typedef __attribute__((ext_vector_type(16))) float f32x16;
typedef __attribute__((ext_vector_type(8))) short bf16x8;

#define MF32(a_, b_, c_) __builtin_amdgcn_mfma_f32_32x32x16_bf16(a_, b_, c_, 0, 0, 0)

__device__ __forceinline__ unsigned short f2bf(float f) {
    union { float f; uint32_t u; } v; v.f = f;
    return (unsigned short)((v.u + 0x7fffu + ((v.u >> 16) & 1u)) >> 16);
}
__device__ __forceinline__ float bf2f(unsigned short h) {
    union { uint32_t u; float f; } v; v.u = ((uint32_t)h) << 16;
    return v.f;
}

// XCD-aware tile mapping. SWZ=0: row-chunk (A-heavy GEMMs). SWZ=1:
// column-slice, x-fastest within slice (B-heavy: QKV, B=25MB).
template <int SWZ>
__device__ __forceinline__ int2 swz_xy() {
    int wid = blockIdx.y * gridDim.x + blockIdx.x;
    const int nwg = gridDim.x * gridDim.y;
    int2 r;
    if (SWZ == 1 && (gridDim.x & 7) == 0) {
        const int sx = gridDim.x >> 3;
        const int c = wid & 7;
        const int l = wid >> 3;
        r.x = c * sx + l % sx;
        r.y = l / sx;
        return r;
    }
    if ((nwg & 7) == 0) {
        const int per = nwg >> 3;
        wid = (wid & 7) * per + (wid >> 3);
    }
    r.x = wid % gridDim.x;
    r.y = wid / gridDim.x;
    return r;
}

struct Ptr4 { const float* p[4]; };
struct Mask4 { const int* p[4]; };

// ---------------- prep kernels ----------------
__global__ void cvt_f32_to_bf16(const float* __restrict__ src,
                                unsigned short* __restrict__ dst, int n4) {
    int i = blockIdx.x * blockDim.x + threadIdx.x;
    if (i >= n4) return;
    float4 v = reinterpret_cast<const float4*>(src)[i];
    ushort4 o;
    o.x = f2bf(v.x); o.y = f2bf(v.y); o.z = f2bf(v.z); o.w = f2bf(v.w);
    reinterpret_cast<ushort4*>(dst)[i] = o;
}

__global__ void cvt5_f32_to_bf16(Ptr4 w4, const float* __restrict__ wo,
                                 unsigned short* __restrict__ wcat,
                                 unsigned short* __restrict__ wobf) {
    const int i = blockIdx.x * blockDim.x + threadIdx.x;
    const int w = i >> 18, r = i & 262143;
    const float* src = (w < 4) ? w4.p[w] : wo;
    unsigned short* dst = (w < 4) ? (wcat + ((size_t)w << 20)) : wobf;
    float4 v = reinterpret_cast<const float4*>(src)[r];
    ushort4 o;
    o.x = f2bf(v.x); o.y = f2bf(v.y); o.z = f2bf(v.z); o.w = f2bf(v.w);
    reinterpret_cast<ushort4*>(dst)[r] = o;
}

// src fp32 [K][Nc] row-major  ->  dst bf16 [Nc][K] row-major (transposed)
__global__ void transpose_cvt(const float* __restrict__ src,
                              unsigned short* __restrict__ dst, int K, int Nc) {
    __shared__ float tile[32][33];
    const int n0 = blockIdx.x * 32, k0 = blockIdx.y * 32;
    const int tx = threadIdx.x & 31, ty = threadIdx.x >> 5;
#pragma unroll
    for (int i = 0; i < 4; ++i) {
        int k = ty + i * 8;
        tile[k][tx] = src[(size_t)(k0 + k) * Nc + n0 + tx];
    }
    __syncthreads();
#pragma unroll
    for (int i = 0; i < 4; ++i) {
        int n = ty + i * 8;
        dst[(size_t)(n0 + n) * K + k0 + tx] = f2bf(tile[tx][n]);
    }
}

__device__ __forceinline__ void gload16(const void* g, void* l) {
    __builtin_amdgcn_global_load_lds(
        (const __attribute__((address_space(1))) void*)g,
        (__attribute__((address_space(3))) void*)l, 16, 0, 0);
}

// ---------------- 128x128 GEMM, 32x32x16 MFMA + fragment-major LDS ----------------
// LDS holds the tile in FRAGMENT order: 16B chunk c = (mt*4+ks)*64 + lane,
// mt = 32-row group (0..3), ks = 16-K slice (0..3). global_load_lds dest is
// linear; the per-lane GLOBAL source is pre-swizzled (HK pattern). ds_read of
// a fragment = lane-linear 16B -> conflict-free on both sides.
// Staging round r (0..3): wave w stages chunk group (mt=r, ks=w):
//   src row = r*32 + (lane&31), k = w*16 + (lane>>5)*8.
// EPI: 0=(acc+bias)*mask->bf16 | 1=acc+bias->bf16 | 2=gelu->bf16
//      3=acc+bias->bf16 (cons)  | 5=mask*(acc+biasA)+bias2->bf16 (QKV)
template <int EPI, int SWZ = 0>
__global__ void gemm_bt(const unsigned short* __restrict__ A,
                        const unsigned short* __restrict__ Bt,
                        void* __restrict__ out, Ptr4 bias, Mask4 masks,
                        const float* __restrict__ biasA,
                        int M, int Nc, int K) {
    __shared__ __attribute__((aligned(16))) unsigned short Als[BM * BK];
    __shared__ __attribute__((aligned(16))) unsigned short Bls[BN * BK];
    const int tid = threadIdx.x;
    const int wave = tid >> 6, lane = tid & 63;
    const int2 bxy = swz_xy<SWZ>();
    const int tileM = bxy.y * BM, tileN = bxy.x * BN;
    const int wr = wave >> 1, wc = wave & 1;     // wave covers rows wr*64, cols wc*64
    const int la32 = lane & 31, lh32 = lane >> 5;

    f32x16 acc[2][2] = {};

    // fragment-major staging sources
    const unsigned short* aSrcs[4];
    const unsigned short* bSrcs[4];
#pragma unroll
    for (int r = 0; r < 4; ++r) {
        aSrcs[r] = A + (size_t)(tileM + r * 32 + la32) * K + wave * 16 + lh32 * 8;
        bSrcs[r] = Bt + (size_t)(tileN + r * 32 + la32) * K + wave * 16 + lh32 * 8;
    }

    for (int k0 = 0; k0 < K; k0 += BK) {
#pragma unroll
        for (int r = 0; r < 4; ++r)
            gload16(aSrcs[r] + k0, &Als[r * 2048 + wave * 512]);
#pragma unroll
        for (int r = 0; r < 4; ++r)
            gload16(bSrcs[r] + k0, &Bls[r * 2048 + wave * 512]);
        __syncthreads();
#pragma unroll
        for (int ks = 0; ks < 4; ++ks) {
            bf16x8 af[2], bfr[2];
#pragma unroll
            for (int mt = 0; mt < 2; ++mt)
                af[mt] = *reinterpret_cast<const bf16x8*>(
                    &Als[((wr * 2 + mt) * 4 + ks) * 512 + lane * 8]);
#pragma unroll
            for (int nt = 0; nt < 2; ++nt)
                bfr[nt] = *reinterpret_cast<const bf16x8*>(
                    &Bls[((wc * 2 + nt) * 4 + ks) * 512 + lane * 8]);
#pragma unroll
            for (int mt = 0; mt < 2; ++mt)
#pragma unroll
                for (int nt = 0; nt < 2; ++nt)
                    acc[mt][nt] = MF32(af[mt], bfr[nt], acc[mt][nt]);
        }
        __syncthreads();
    }

    // ---- epilogue (C/D: col=lane&31, row=(reg&3)+8*(reg>>2)+4*(lane>>5)) ----
    unsigned short* outB = (unsigned short*)out;
    const int* mp = nullptr;
    if constexpr (EPI == 0) mp = masks.p[tileN >> 10];
    if constexpr (EPI == 5) mp = masks.p[(tileN >> 10) & 3];
    const float* bp = nullptr;
    const float* bp2 = nullptr;
    if constexpr (EPI == 5) bp2 = bias.p[tileN >> 12];
    else bp = bias.p[tileN >> 10];

#pragma unroll
    for (int nt = 0; nt < 2; ++nt) {
        const int gcol = tileN + (wc * 2 + nt) * 32 + la32;
        float bv, bv2 = 0.f;
        if constexpr (EPI == 5) { bv = biasA[gcol]; bv2 = bp2[gcol & (DM - 1)]; }
        else bv = bp[gcol & (DM - 1)];
#pragma unroll
        for (int mt = 0; mt < 2; ++mt) {
#pragma unroll
            for (int rg = 0; rg < 4; ++rg) {
                const int rowb = tileM + (wr * 2 + mt) * 32 + lh32 * 4 + rg * 8;
#pragma unroll
                for (int i = 0; i < 4; ++i) {
                    const int grow = rowb + i;
                    float val = acc[mt][nt][rg * 4 + i] + bv;
                    if constexpr (EPI == 0) {
                        val *= (float)mp[grow];
                        outB[(size_t)grow * Nc + gcol] = f2bf(val);
                    } else if constexpr (EPI == 1) {
                        outB[(size_t)grow * Nc + gcol] = f2bf(val);
                    } else if constexpr (EPI == 2) {
                        val = 0.5f * val * (1.0f + erff(val * 0.70710678118654752f));
                        outB[(size_t)grow * Nc + gcol] = f2bf(val);
                    } else if constexpr (EPI == 3) {
                        outB[(size_t)grow * Nc + gcol] = f2bf(val);
                    } else { // EPI == 5
                        val = (float)mp[grow] * val + bv2;
                        outB[(size_t)grow * Nc + gcol] = f2bf(val);
                    }
                }
            }
        }
    }
}

// ---------------- weight-fusion prep GEMM (same 32x32 core, strided) ----------------
template <bool TSTORE>
__global__ void gemm_prep(const unsigned short* __restrict__ A0, int lda, int aZoff,
                          const unsigned short* __restrict__ Bt, int ldb,
                          unsigned short* __restrict__ out, int ldc, int cZstride,
                          int K) {
    __shared__ __attribute__((aligned(16))) unsigned short Als[BM * BK];
    __shared__ __attribute__((aligned(16))) unsigned short Bls[BN * BK];
    const unsigned short* A = A0 + (size_t)blockIdx.z * aZoff;
    const int tid = threadIdx.x;
    const int wave = tid >> 6, lane = tid & 63;
    const int2 bxy = swz_xy<0>();
    const int tileM = bxy.y * BM, tileN = bxy.x * BN;
    const int wr = wave >> 1, wc = wave & 1;
    const int la32 = lane & 31, lh32 = lane >> 5;

    f32x16 acc[2][2] = {};

    const unsigned short* aSrcs[4];
    const unsigned short* bSrcs[4];
#pragma unroll
    for (int r = 0; r < 4; ++r) {
        aSrcs[r] = A + (size_t)(tileM + r * 32 + la32) * lda + wave * 16 + lh32 * 8;
        bSrcs[r] = Bt + (size_t)(tileN + r * 32 + la32) * ldb + wave * 16 + lh32 * 8;
    }

    for (int k0 = 0; k0 < K; k0 += BK) {
#pragma unroll
        for (int r = 0; r < 4; ++r)
            gload16(aSrcs[r] + k0, &Als[r * 2048 + wave * 512]);
#pragma unroll
        for (int r = 0; r < 4; ++r)
            gload16(bSrcs[r] + k0, &Bls[r * 2048 + wave * 512]);
        __syncthreads();
#pragma unroll
        for (int ks = 0; ks < 4; ++ks) {
            bf16x8 af[2], bfr[2];
#pragma unroll
            for (int mt = 0; mt < 2; ++mt)
                af[mt] = *reinterpret_cast<const bf16x8*>(
                    &Als[((wr * 2 + mt) * 4 + ks) * 512 + lane * 8]);
#pragma unroll
            for (int nt = 0; nt < 2; ++nt)
                bfr[nt] = *reinterpret_cast<const bf16x8*>(
                    &Bls[((wc * 2 + nt) * 4 + ks) * 512 + lane * 8]);
#pragma unroll
            for (int mt = 0; mt < 2; ++mt)
#pragma unroll
                for (int nt = 0; nt < 2; ++nt)
                    acc[mt][nt] = MF32(af[mt], bfr[nt], acc[mt][nt]);
        }
        __syncthreads();
    }

#pragma unroll
    for (int nt = 0; nt < 2; ++nt) {
        const int gcol = tileN + (wc * 2 + nt) * 32 + la32;
#pragma unroll
        for (int mt = 0; mt < 2; ++mt) {
#pragma unroll
            for (int rg = 0; rg < 4; ++rg) {
                const int g0 = tileM + (wr * 2 + mt) * 32 + lh32 * 4 + rg * 8;
                if constexpr (TSTORE) {
                    ushort4 o4;
                    o4.x = f2bf(acc[mt][nt][rg * 4 + 0]);
                    o4.y = f2bf(acc[mt][nt][rg * 4 + 1]);
                    o4.z = f2bf(acc[mt][nt][rg * 4 + 2]);
                    o4.w = f2bf(acc[mt][nt][rg * 4 + 3]);
                    const size_t drow = ((size_t)(gcol >> 10) << 12) +
                                        ((size_t)(g0 >> 10) << 10) + (gcol & 1023);
                    *reinterpret_cast<ushort4*>(out + drow * 1024 + (g0 & 1023)) = o4;
                } else {
#pragma unroll
                    for (int i = 0; i < 4; ++i) {
                        const int grow = g0 + i;
                        out[(size_t)grow * ldc + (size_t)blockIdx.z * cZstride + gcol] =
                            f2bf(acc[mt][nt][rg * 4 + i]);
                    }
                }
            }
        }
    }
}

// ---------------- bias folding ----------------
__global__ void fuse_biasA(Ptr4 bmods, const unsigned short* __restrict__ Btqkv,
                           float* __restrict__ biasA) {
    const int o = blockIdx.x * 4 + (threadIdx.x >> 6);
    const int lane = threadIdx.x & 63;
    const int qk = o >> 12, im = (o >> 10) & 3, j = o & 1023;
    const float* b = bmods.p[im];
    const unsigned short* wrow = Btqkv + ((size_t)(qk << 10) + j) * 1024;
    float s = 0.f;
    for (int t = lane; t < 1024; t += 64) s += b[t] * bf2f(wrow[t]);
#pragma unroll
    for (int off = 32; off >= 1; off >>= 1) s += __shfl_xor(s, off, 64);
    if (lane == 0) biasA[o] = s;
}

__global__ void fuse_biasH(const float* __restrict__ bo, const float* __restrict__ bg1,
                           const unsigned short* __restrict__ Btg1,
                           float* __restrict__ biasH) {
    const int c = blockIdx.x * 4 + (threadIdx.x >> 6);
    const int lane = threadIdx.x & 63;
    const unsigned short* row = Btg1 + (size_t)c * 4096;
    float s = 0.f;
    for (int t = lane; t < 4096; t += 64) s += bo[t & 1023] * bf2f(row[t]);
#pragma unroll
    for (int off = 32; off >= 1; off >>= 1) s += __shfl_xor(s, off, 64);
    if (lane == 0) biasH[c] = s + bg1[c];
}

// ---------------- tiny 4-token attention, fused-QKV layout ----------------
__global__ void attn4F(const unsigned short* __restrict__ qkvF,
                       unsigned short* __restrict__ ctx) {
    const int n = blockIdx.x;
    const int h = threadIdx.x >> 6;
    const int lane = threadIdx.x & 63;
    const size_t base = (size_t)n * 12288 + h * HD + lane * 4;

    float q[4][4], k[4][4], v[4][4];
#pragma unroll
    for (int m = 0; m < 4; ++m) {
        ushort4 uq = *reinterpret_cast<const ushort4*>(&qkvF[base + m * 1024]);
        ushort4 uk = *reinterpret_cast<const ushort4*>(&qkvF[base + m * 1024 + 4096]);
        ushort4 uv = *reinterpret_cast<const ushort4*>(&qkvF[base + m * 1024 + 8192]);
        q[m][0] = bf2f(uq.x); q[m][1] = bf2f(uq.y); q[m][2] = bf2f(uq.z); q[m][3] = bf2f(uq.w);
        k[m][0] = bf2f(uk.x); k[m][1] = bf2f(uk.y); k[m][2] = bf2f(uk.z); k[m][3] = bf2f(uk.w);
        v[m][0] = bf2f(uv.x); v[m][1] = bf2f(uv.y); v[m][2] = bf2f(uv.z); v[m][3] = bf2f(uv.w);
    }

    float s[4][4];
#pragma unroll
    for (int qi = 0; qi < 4; ++qi)
#pragma unroll
        for (int ki = 0; ki < 4; ++ki)
            s[qi][ki] = q[qi][0] * k[ki][0] + q[qi][1] * k[ki][1] +
                        q[qi][2] * k[ki][2] + q[qi][3] * k[ki][3];
#pragma unroll
    for (int off = 32; off >= 1; off >>= 1) {
#pragma unroll
        for (int qi = 0; qi < 4; ++qi)
#pragma unroll
            for (int ki = 0; ki < 4; ++ki)
                s[qi][ki] += __shfl_xor(s[qi][ki], off, 64);
    }

#pragma unroll
    for (int qi = 0; qi < 4; ++qi) {
        float s0 = s[qi][0] * 0.0625f, s1 = s[qi][1] * 0.0625f;
        float s2 = s[qi][2] * 0.0625f, s3 = s[qi][3] * 0.0625f;
        float mx = fmaxf(fmaxf(s0, s1), fmaxf(s2, s3));
        float e0 = __expf(s0 - mx), e1 = __expf(s1 - mx);
        float e2 = __expf(s2 - mx), e3 = __expf(s3 - mx);
        float inv = 1.0f / (e0 + e1 + e2 + e3);
        e0 *= inv; e1 *= inv; e2 *= inv; e3 *= inv;
        ushort4 o;
        o.x = f2bf(e0 * v[0][0] + e1 * v[1][0] + e2 * v[2][0] + e3 * v[3][0]);
        o.y = f2bf(e0 * v[0][1] + e1 * v[1][1] + e2 * v[2][1] + e3 * v[3][1]);
        o.z = f2bf(e0 * v[0][2] + e1 * v[1][2] + e2 * v[2][2] + e3 * v[3][2]);
        o.w = f2bf(e0 * v[0][3] + e1 * v[1][3] + e2 * v[2][3] + e3 * v[3][3]);
        *reinterpret_cast<ushort4*>(&ctx[(size_t)n * 4096 + qi * 1024 + h * HD + lane * 4]) = o;
    }
}

// ---------------- tiny 4-token attention, legacy layout (plan A) ----------------
__global__ void attn4(const unsigned short* __restrict__ qkv,
                      unsigned short* __restrict__ ctx) {
    const int n = blockIdx.x;
    const int h = threadIdx.x >> 6;
    const int lane = threadIdx.x & 63;
    const size_t base = (size_t)n * 4 * 3072 + h * HD + lane * 4;

    float q[4][4], k[4][4], v[4][4];
#pragma unroll
    for (int m = 0; m < 4; ++m) {
        ushort4 uq = *reinterpret_cast<const ushort4*>(&qkv[base + (size_t)m * 3072]);
        ushort4 uk = *reinterpret_cast<const ushort4*>(&qkv[base + (size_t)m * 3072 + 1024]);
        ushort4 uv = *reinterpret_cast<const ushort4*>(&qkv[base + (size_t)m * 3072 + 2048]);
        q[m][0] = bf2f(uq.x); q[m][1] = bf2f(uq.y); q[m][2] = bf2f(uq.z); q[m][3] = bf2f(uq.w);
        k[m][0] = bf2f(uk.x); k[m][1] = bf2f(uk.y); k[m][2] = bf2f(uk.z); k[m][3] = bf2f(uk.w);
        v[m][0] = bf2f(uv.x); v[m][1] = bf2f(uv.y); v[m][2] = bf2f(uv.z); v[m][3] = bf2f(uv.w);
    }

    float s[4][4];
#pragma unroll
    for (int qi = 0; qi < 4; ++qi)
#pragma unroll
        for (int ki = 0; ki < 4; ++ki)
            s[qi][ki] = q[qi][0] * k[ki][0] + q[qi][1] * k[ki][1] +
                        q[qi][2] * k[ki][2] + q[qi][3] * k[ki][3];
#pragma unroll
    for (int off = 32; off >= 1; off >>= 1) {
#pragma unroll
        for (int qi = 0; qi < 4; ++qi)
#pragma unroll
            for (int ki = 0; ki < 4; ++ki)
                s[qi][ki] += __shfl_xor(s[qi][ki], off, 64);
    }

#pragma unroll
    for (int qi = 0; qi < 4; ++qi) {
        float s0 = s[qi][0] * 0.0625f, s1 = s[qi][1] * 0.0625f;
        float s2 = s[qi][2] * 0.0625f, s3 = s[qi][3] * 0.0625f;
        float mx = fmaxf(fmaxf(s0, s1), fmaxf(s2, s3));
        float e0 = __expf(s0 - mx), e1 = __expf(s1 - mx);
        float e2 = __expf(s2 - mx), e3 = __expf(s3 - mx);
        float inv = 1.0f / (e0 + e1 + e2 + e3);
        e0 *= inv; e1 *= inv; e2 *= inv; e3 *= inv;
        ushort4 o;
        o.x = f2bf(e0 * v[0][0] + e1 * v[1][0] + e2 * v[2][0] + e3 * v[3][0]);
        o.y = f2bf(e0 * v[0][1] + e1 * v[1][1] + e2 * v[2][1] + e3 * v[3][1]);
        o.z = f2bf(e0 * v[0][2] + e1 * v[1][2] + e2 * v[2][2] + e3 * v[3][2]);
        o.w = f2bf(e0 * v[0][3] + e1 * v[1][3] + e2 * v[2][3] + e3 * v[3][3]);
        *reinterpret_cast<ushort4*>(&ctx[(size_t)(n * 4 + qi) * 1024 + h * HD + lane * 4]) = o;
    }
}

// ---------------- residual + LayerNorm (bf16 consensus input) ----------------
__global__ void resid_ln(const unsigned short* __restrict__ cons,
                         const float* __restrict__ feat,
                         const float* __restrict__ g, const float* __restrict__ b,
                         float* __restrict__ out) {
    const int row = blockIdx.x;
    const int t = threadIdx.x;
    const size_t base = (size_t)row * DM + t * 4;
    ushort4 c4 = *reinterpret_cast<const ushort4*>(&cons[base]);
    float4 f = *reinterpret_cast<const float4*>(&feat[base]);
    float y0 = bf2f(c4.x) + f.x, y1 = bf2f(c4.y) + f.y;
    float y2 = bf2f(c4.z) + f.z, y3 = bf2f(c4.w) + f.w;
    float sum = y0 + y1 + y2 + y3;
    float sq = y0 * y0 + y1 * y1 + y2 * y2 + y3 * y3;
#pragma unroll
    for (int off = 32; off >= 1; off >>= 1) {
        sum += __shfl_xor(sum, off, 64);
        sq += __shfl_xor(sq, off, 64);
    }
    __shared__ float rs[4], rq[4];
    const int wv = t >> 6, ln = t & 63;
    if (ln == 0) { rs[wv] = sum; rq[wv] = sq; }
    __syncthreads();
    sum = rs[0] + rs[1] + rs[2] + rs[3];
    sq = rq[0] + rq[1] + rq[2] + rq[3];
    const float mu = sum * (1.0f / DM);
    const float var = sq * (1.0f / DM) - mu * mu;
    const float rstd = rsqrtf(var + 1e-5f);
    float4 gg = *reinterpret_cast<const float4*>(&g[t * 4]);
    float4 bb = *reinterpret_cast<const float4*>(&b[t * 4]);
    float4 o;
    o.x = (y0 - mu) * rstd * gg.x + bb.x;
    o.y = (y1 - mu) * rstd * gg.y + bb.y;
    o.z = (y2 - mu) * rstd * gg.z + bb.z;
    o.w = (y3 - mu) * rstd * gg.w + bb.w;
    *reinterpret_cast<float4*>(&out[base]) = o;
}

// ---------------- launch ----------------
extern "C" void kernel_launch(void* const* d_in, const int* in_sizes, int n_in,
                              void* d_out, int out_size, void* d_ws, size_t ws_size,
                              hipStream_t stream) {
    (void)in_sizes; (void)n_in; (void)out_size;
    const float* feat = (const float*)d_in[0];
    const int* am = (const int*)d_in[1];
    const int* dmk = (const int*)d_in[2];
    const int* em = (const int*)d_in[3];
    const int* hmk = (const int*)d_in[4];
    const float* Wa = (const float*)d_in[5];  const float* ba = (const float*)d_in[6];
    const float* Wd = (const float*)d_in[7];  const float* bd = (const float*)d_in[8];
    const float* We = (const float*)d_in[9];  const float* be = (const float*)d_in[10];
    const float* Wh = (const float*)d_in[11]; const float* bh = (const float*)d_in[12];
    const float* Wq = (const float*)d_in[13]; const float* bq = (const float*)d_in[14];
    const float* Wk = (const float*)d_in[15]; const float* bk = (const float*)d_in[16];
    const float* Wv = (const float*)d_in[17]; const float* bv = (const float*)d_in[18];
    const float* Wo = (const float*)d_in[19]; const float* bo = (const float*)d_in[20];
    const float* Wg1 = (const float*)d_in[21]; const float* bg1 = (const float*)d_in[22];
    const float* Wg2 = (const float*)d_in[23]; const float* bg2 = (const float*)d_in[24];
    const float* lng = (const float*)d_in[25]; const float* lnb = (const float*)d_in[26];

    char* ws = (char*)d_ws;
    size_t off = 0;
    auto take = [&](size_t bytes) -> char* {
        char* r = ws + off;
        off = (off + bytes + 255) & ~(size_t)255;
        return r;
    };
    // ---- fixed allocations (~97 MB) ----
    unsigned short* featB = (unsigned short*)take((size_t)NT * DM * 2);
    unsigned short* Btqkv = (unsigned short*)take((size_t)3 * DM * DM * 2);
    unsigned short* Btg1  = (unsigned short*)take((size_t)2 * DM * 4 * DM * 2);
    unsigned short* Btg2  = (unsigned short*)take((size_t)DM * 2 * DM * 2);
    unsigned short* Wcat  = (unsigned short*)take((size_t)4 * DM * DM * 2);
    unsigned short* Wo_bf = (unsigned short*)take((size_t)DM * DM * 2);
    unsigned short* Btf   = (unsigned short*)take((size_t)12 * DM * DM * 2);
    unsigned short* Btm1  = (unsigned short*)take((size_t)8 * DM * DM * 2);
    float* biasA          = (float*)take((size_t)12 * DM * 4);
    float* biasH          = (float*)take((size_t)2 * DM * 4);
    const size_t fixed = off;

    // shared prep
    cvt_f32_to_bf16<<<dim3((NT * DM / 4 + 255) / 256), dim3(256), 0, stream>>>(
        feat, featB, NT * DM / 4);
    auto tl = [&](const float* src, unsigned short* dst, int K, int Nc) {
        transpose_cvt<<<dim3(Nc / 32, K / 32), dim3(256), 0, stream>>>(src, dst, K, Nc);
    };
    tl(Wq, Btqkv, DM, DM);
    tl(Wk, Btqkv + (size_t)DM * DM, DM, DM);
    tl(Wv, Btqkv + (size_t)2 * DM * DM, DM, DM);
    tl(Wg1, Btg1, 4 * DM, 2 * DM);
    tl(Wg2, Btg2, 2 * DM, DM);

    Ptr4 bmods{{ba, bd, be, bh}};
    Ptr4 bqkv{{bq, bk, bv, nullptr}};
    Ptr4 bH{{biasH, biasH + DM, nullptr, nullptr}};
    Ptr4 bg24{{bg2, nullptr, nullptr, nullptr}};
    Mask4 mnull{{nullptr, nullptr, nullptr, nullptr}};

    // ---- plan B sizing: largest T2 that fits ----
    const size_t ctxBytes = (size_t)NT * 4096 * 2;
    const size_t hBytes = (size_t)NT * 2048 * 2 + 512;
    int T2 = 0;
    {
        const int cands[4] = {8192, 4096, 2048, 1024};
        for (int ci = 0; ci < 4; ++ci) {
            int c = cands[ci];
            size_t chunkB = (size_t)c * 24576 + 512;
            size_t regHB = chunkB > hBytes ? chunkB : hBytes;
            if (fixed + ctxBytes + 256 + regHB + 4096 <= ws_size) { T2 = c; break; }
        }
    }

    if (T2 > 0) {
        char* regX = take(ctxBytes);
        size_t chunkB = (size_t)T2 * 24576 + 512;
        char* regH = take(chunkB > hBytes ? chunkB : hBytes);
        unsigned short* ctx = (unsigned short*)regX;    // ctx bf16 [NT][4096]
        unsigned short* cons = (unsigned short*)regX;   // consensus bf16 (aliases ctx)
        unsigned short* h = (unsigned short*)regH;      // gelu-h bf16 [NT][2048]
        unsigned short* qkvF = (unsigned short*)regH;   // qkv chunk bf16 [T2][12288]

        // fused-weight prep (one merged convert launch)
        Ptr4 w4{{Wa, Wd, We, Wh}};
        cvt5_f32_to_bf16<<<dim3(5 * DM * DM / 4 / 256), dim3(256), 0, stream>>>(
            w4, Wo, Wcat, Wo_bf);
        gemm_prep<true><<<dim3(24, 32, 1), dim3(256), 0, stream>>>(
            Wcat, DM, 0, Btqkv, DM, Btf, 0, 0, DM);
        gemm_prep<false><<<dim3(8, 16, 4), dim3(256), 0, stream>>>(
            Btg1, 4 * DM, DM, Wo_bf, DM, Btm1, 4 * DM, DM, DM);
        fuse_biasA<<<dim3(12 * DM / 4), dim3(256), 0, stream>>>(bmods, Btqkv, biasA);
        fuse_biasH<<<dim3(2 * DM / 4), dim3(256), 0, stream>>>(bo, bg1, Btg1, biasH);

        // fused QKV (column-sliced XCD mapping) + attention
        for (int t0 = 0; t0 < NT; t0 += T2) {
            Mask4 mk{{am + t0, dmk + t0, em + t0, hmk + t0}};
            gemm_bt<5, 1><<<dim3(96, T2 / BM), dim3(256), 0, stream>>>(
                featB + (size_t)t0 * DM, Btf, (void*)qkvF, bqkv, mk, biasA,
                T2, 12 * DM, DM);
            attn4F<<<dim3(T2), dim3(256), 0, stream>>>(qkvF, ctx + (size_t)t0 * 4096);
        }
        // MLP1 (fused Wo@Wg1) + GELU: h[NT][2048]
        gemm_bt<2><<<dim3(16, NT / BM), dim3(256), 0, stream>>>(
            ctx, Btm1, (void*)h, bH, mnull, nullptr, NT, 2 * DM, 4 * DM);
        // MLP2: cons bf16 [NT][1024]
        gemm_bt<3><<<dim3(8, NT / BM), dim3(256), 0, stream>>>(
            h, Btg2, (void*)cons, bg24, mnull, nullptr, NT, DM, 2 * DM);
        // residual + LayerNorm
        resid_ln<<<dim3(NT), dim3(256), 0, stream>>>(cons, feat, lng, lnb, (float*)d_out);
        return;
    }

    // ---- plan A fallback (fully-chunked unfused pipeline) ----
    unsigned short* Bt1 = (unsigned short*)take((size_t)4 * DM * DM * 2);
    unsigned short* Bto = (unsigned short*)take((size_t)DM * DM * 2);
    tl(Wa, Bt1, DM, DM);
    tl(Wd, Bt1 + (size_t)DM * DM, DM, DM);
    tl(We, Bt1 + (size_t)2 * DM * DM, DM, DM);
    tl(Wh, Bt1 + (size_t)3 * DM * DM, DM, DM);
    tl(Wo, Bto, DM, DM);

    Ptr4 b1{{ba, bd, be, bh}};
    Ptr4 bo4{{bo, nullptr, nullptr, nullptr}};
    Ptr4 bg14{{bg1, bg1 + DM, nullptr, nullptr}};

    const size_t avail = (ws_size > off) ? (ws_size - off) : 0;
    int T = 2048;
    while (T > 128 && ((size_t)T * 40960 + 4096) > avail) T >>= 1;
    unsigned short* bufA = (unsigned short*)take((size_t)T * 4096 * 2);
    unsigned short* bufB = (unsigned short*)take((size_t)T * 4 * 3072 * 2);
    unsigned short* bufC = (unsigned short*)take((size_t)T * 4 * 1024 * 2);

    const int nch = NT / T;
    for (int c = 0; c < nch; ++c) {
        const int t0 = c * T;
        Mask4 mk{{am + t0, dmk + t0, em + t0, hmk + t0}};
        gemm_bt<0><<<dim3(4 * DM / BN, T / BM), dim3(256), 0, stream>>>(
            featB + (size_t)t0 * DM, Bt1, (void*)bufA, b1, mk, nullptr, T, 4 * DM, DM);
        gemm_bt<1><<<dim3(3 * DM / BN, 4 * T / BM), dim3(256), 0, stream>>>(
            bufA, Btqkv, (void*)bufB, bqkv, mnull, nullptr, 4 * T, 3 * DM, DM);
        attn4<<<dim3(T), dim3(256), 0, stream>>>(bufB, bufC);
        gemm_bt<1><<<dim3(DM / BN, 4 * T / BM), dim3(256), 0, stream>>>(
            bufC, Bto, (void*)bufA, bo4, mnull, nullptr, 4 * T, DM, DM);
        gemm_bt<2><<<dim3(2 * DM / BN, T / BM), dim3(256), 0, stream>>>(
            bufA, Btg1, (void*)bufC, bg14, mnull, nullptr, T, 2 * DM, 4 * DM);
        gemm_bt<3><<<dim3(DM / BN, T / BM), dim3(256), 0, stream>>>(
            bufC, Btg2, (void*)bufB, bg24, mnull, nullptr, T, DM, 2 * DM);
        resid_ln<<<dim3(T), dim3(256), 0, stream>>>(
            bufB, feat + (size_t)t0 * DM, lng, lnb,
            (float*)d_out + (size_t)t0 * DM);
    }
}

// Round 12
// 741.792 us; speedup vs baseline: 1.3321x; 1.3321x over previous
//
#include <hip/hip_runtime.h>
#include <cstdint>
#include <cstddef>

// ---------------- constants ----------------
#define DM   1024          // model dim
#define NT   8192          // B*L tokens
#define HD   256
#define BM 128
#define BN 128
#define BK 64

typedef __attribute__((ext_vector_type(4))) float f32x4;
typedef __attribute__((ext_vector_type(8))) short bf16x8;

#define MF(a_, b_, c_) __builtin_amdgcn_mfma_f32_16x16x32_bf16(a_, b_, c_, 0, 0, 0)

__device__ __forceinline__ unsigned short f2bf(float f) {
    union { float f; uint32_t u; } v; v.f = f;
    return (unsigned short)((v.u + 0x7fffu + ((v.u >> 16) & 1u)) >> 16);
}
__device__ __forceinline__ float bf2f(unsigned short h) {
    union { uint32_t u; float f; } v; v.u = ((uint32_t)h) << 16;
    return v.f;
}

// XCD-aware tile mapping. SWZ=0: row-chunk (A-heavy). SWZ=1: column-slice
// (B-heavy: QKV).
template <int SWZ>
__device__ __forceinline__ int2 swz_xy() {
    int wid = blockIdx.y * gridDim.x + blockIdx.x;
    const int nwg = gridDim.x * gridDim.y;
    int2 r;
    if (SWZ == 1 && (gridDim.x & 7) == 0) {
        const int sx = gridDim.x >> 3;
        const int c = wid & 7;
        const int l = wid >> 3;
        r.x = c * sx + l % sx;
        r.y = l / sx;
        return r;
    }
    if ((nwg & 7) == 0) {
        const int per = nwg >> 3;
        wid = (wid & 7) * per + (wid >> 3);
    }
    r.x = wid % gridDim.x;
    r.y = wid / gridDim.x;
    return r;
}

struct Ptr4 { const float* p[4]; };
struct Mask4 { const int* p[4]; };

// ---------------- prep kernels ----------------
__global__ void cvt_f32_to_bf16(const float* __restrict__ src,
                                unsigned short* __restrict__ dst, int n4) {
    int i = blockIdx.x * blockDim.x + threadIdx.x;
    if (i >= n4) return;
    float4 v = reinterpret_cast<const float4*>(src)[i];
    ushort4 o;
    o.x = f2bf(v.x); o.y = f2bf(v.y); o.z = f2bf(v.z); o.w = f2bf(v.w);
    reinterpret_cast<ushort4*>(dst)[i] = o;
}

__global__ void cvt5_f32_to_bf16(Ptr4 w4, const float* __restrict__ wo,
                                 unsigned short* __restrict__ wcat,
                                 unsigned short* __restrict__ wobf) {
    const int i = blockIdx.x * blockDim.x + threadIdx.x;
    const int w = i >> 18, r = i & 262143;
    const float* src = (w < 4) ? w4.p[w] : wo;
    unsigned short* dst = (w < 4) ? (wcat + ((size_t)w << 20)) : wobf;
    float4 v = reinterpret_cast<const float4*>(src)[r];
    ushort4 o;
    o.x = f2bf(v.x); o.y = f2bf(v.y); o.z = f2bf(v.z); o.w = f2bf(v.w);
    reinterpret_cast<ushort4*>(dst)[r] = o;
}

// src fp32 [K][Nc] row-major  ->  dst bf16 [Nc][K] row-major (transposed)
__global__ void transpose_cvt(const float* __restrict__ src,
                              unsigned short* __restrict__ dst, int K, int Nc) {
    __shared__ float tile[32][33];
    const int n0 = blockIdx.x * 32, k0 = blockIdx.y * 32;
    const int tx = threadIdx.x & 31, ty = threadIdx.x >> 5;
#pragma unroll
    for (int i = 0; i < 4; ++i) {
        int k = ty + i * 8;
        tile[k][tx] = src[(size_t)(k0 + k) * Nc + n0 + tx];
    }
    __syncthreads();
#pragma unroll
    for (int i = 0; i < 4; ++i) {
        int n = ty + i * 8;
        dst[(size_t)(n0 + n) * K + k0 + tx] = f2bf(tile[tx][n]);
    }
}

__device__ __forceinline__ void gload16(const void* g, void* l) {
    __builtin_amdgcn_global_load_lds(
        (const __attribute__((address_space(1))) void*)g,
        (__attribute__((address_space(3))) void*)l, 16, 0, 0);
}

// ---------------- 128x128 GEMM, BK=64 + both-sides XOR swizzle (R10 core) ----------------
// EPI: 0=(acc+bias)*mask->bf16 | 1=acc+bias->bf16 | 2=gelu->bf16
//      3=acc+bias->bf16 (cons)  | 5=mask*(acc+biasA)+bias2->bf16 (QKV)
template <int EPI, int SWZ = 0>
__global__ void gemm_bt(const unsigned short* __restrict__ A,
                        const unsigned short* __restrict__ Bt,
                        void* __restrict__ out, Ptr4 bias, Mask4 masks,
                        const float* __restrict__ biasA,
                        int M, int Nc, int K) {
    __shared__ __attribute__((aligned(16))) unsigned short Als[BM * BK];
    __shared__ __attribute__((aligned(16))) unsigned short Bls[BN * BK];
    const int tid = threadIdx.x;
    const int wave = tid >> 6, lane = tid & 63;
    const int2 bxy = swz_xy<SWZ>();
    const int tileM = bxy.y * BM, tileN = bxy.x * BN;
    const int wr = wave >> 1, wc = wave & 1;
    const int la = lane & 15, lh = lane >> 4;

    f32x4 acc[4][4] = {};

    const int sr = tid >> 3;
    const int sb = (tid & 7) * 16;
    const int ssw = (sb ^ ((sr & 7) << 4)) >> 1;
    const unsigned short* aSrcs[4];
    const unsigned short* bSrcs[4];
#pragma unroll
    for (int c = 0; c < 4; ++c) {
        aSrcs[c] = A + (size_t)(tileM + c * 32 + sr) * K + ssw;
        bSrcs[c] = Bt + (size_t)(tileN + c * 32 + sr) * K + ssw;
    }

    for (int k0 = 0; k0 < K; k0 += BK) {
#pragma unroll
        for (int c = 0; c < 4; ++c)
            gload16(aSrcs[c] + k0, &Als[wave * 512 + c * 2048]);
#pragma unroll
        for (int c = 0; c < 4; ++c)
            gload16(bSrcs[c] + k0, &Bls[wave * 512 + c * 2048]);
        __syncthreads();
#pragma unroll
        for (int ks = 0; ks < 2; ++ks) {
            const int uo = ((ks * 4 + lh) ^ (la & 7)) * 8;
            bf16x8 af[4], bfr[4];
#pragma unroll
            for (int m = 0; m < 4; ++m)
                af[m] = *reinterpret_cast<const bf16x8*>(&Als[(wr * 64 + m * 16 + la) * BK + uo]);
#pragma unroll
            for (int n = 0; n < 4; ++n)
                bfr[n] = *reinterpret_cast<const bf16x8*>(&Bls[(wc * 64 + n * 16 + la) * BK + uo]);
#pragma unroll
            for (int m = 0; m < 4; ++m)
#pragma unroll
                for (int n = 0; n < 4; ++n)
                    acc[m][n] = MF(af[m], bfr[n], acc[m][n]);
        }
        __syncthreads();
    }

    const int rowT = tileM + wr * 64 + lh * 4;
    const int colT = tileN + wc * 64;
    unsigned short* outB = (unsigned short*)out;

    float mv[4][4];
    if constexpr (EPI == 0 || EPI == 5) {
        const int* mp = (EPI == 0) ? masks.p[tileN >> 10] : masks.p[(tileN >> 10) & 3];
#pragma unroll
        for (int m = 0; m < 4; ++m)
#pragma unroll
            for (int i = 0; i < 4; ++i)
                mv[m][i] = (float)mp[rowT + m * 16 + i];
    }
    const float* bp = nullptr;
    const float* bp2 = nullptr;
    if constexpr (EPI == 5) bp2 = bias.p[tileN >> 12];
    else bp = bias.p[tileN >> 10];

#pragma unroll
    for (int n = 0; n < 4; ++n) {
        const int gcol = colT + n * 16 + la;
        float bv, bv2 = 0.f;
        if constexpr (EPI == 5) { bv = biasA[gcol]; bv2 = bp2[gcol & (DM - 1)]; }
        else bv = bp[gcol & (DM - 1)];
#pragma unroll
        for (int m = 0; m < 4; ++m) {
#pragma unroll
            for (int i = 0; i < 4; ++i) {
                const int grow = rowT + m * 16 + i;
                float val = acc[m][n][i] + bv;
                if constexpr (EPI == 0) {
                    val *= mv[m][i];
                    outB[(size_t)grow * Nc + gcol] = f2bf(val);
                } else if constexpr (EPI == 1) {
                    outB[(size_t)grow * Nc + gcol] = f2bf(val);
                } else if constexpr (EPI == 2) {
                    val = 0.5f * val * (1.0f + erff(val * 0.70710678118654752f));
                    outB[(size_t)grow * Nc + gcol] = f2bf(val);
                } else if constexpr (EPI == 3) {
                    outB[(size_t)grow * Nc + gcol] = f2bf(val);
                } else { // EPI == 5
                    val = mv[m][i] * val + bv2;
                    outB[(size_t)grow * Nc + gcol] = f2bf(val);
                }
            }
        }
    }
}

// ---------------- 128x128 GEMM, 2 waves x (128x64)/wave: high register reuse ----------------
// Same BK=64 + both-sides XOR swizzle as gemm_bt; wave w owns all 128 rows x
// cols [w*64, w*64+64). Per K-step per wave: 24KB LDS read, 64 MFMA
// (43.7 FLOP/LDS-byte vs 32 for the 4-wave core). acc = 128 VGPR.
template <int EPI, int SWZ = 0>
__global__ __launch_bounds__(128, 2)
void gemm_bt2(const unsigned short* __restrict__ A,
              const unsigned short* __restrict__ Bt,
              void* __restrict__ out, Ptr4 bias, Mask4 masks,
              const float* __restrict__ biasA,
              int M, int Nc, int K) {
    __shared__ __attribute__((aligned(16))) unsigned short Als[BM * BK];
    __shared__ __attribute__((aligned(16))) unsigned short Bls[BN * BK];
    const int tid = threadIdx.x;
    const int wave = tid >> 6, lane = tid & 63;
    const int2 bxy = swz_xy<SWZ>();
    const int tileM = bxy.y * BM, tileN = bxy.x * BN;
    const int la = lane & 15, lh = lane >> 4;

    f32x4 acc[8][4] = {};

    // staging: 128 threads cover 16 rows x 8 units per chunk; 8 chunks each for A,B
    const int sr = tid >> 3;                 // 0..15
    const int sb = (tid & 7) * 16;
    const int ssw = (sb ^ ((sr & 7) << 4)) >> 1;
    const unsigned short* aBase = A + (size_t)(tileM + sr) * K + ssw;
    const unsigned short* bBase = Bt + (size_t)(tileN + sr) * K + ssw;

    for (int k0 = 0; k0 < K; k0 += BK) {
#pragma unroll
        for (int c = 0; c < 8; ++c)
            gload16(aBase + (size_t)(c * 16) * K + k0, &Als[c * 1024 + wave * 512]);
#pragma unroll
        for (int c = 0; c < 8; ++c)
            gload16(bBase + (size_t)(c * 16) * K + k0, &Bls[c * 1024 + wave * 512]);
        __syncthreads();
#pragma unroll
        for (int ks = 0; ks < 2; ++ks) {
            const int uo = ((ks * 4 + lh) ^ (la & 7)) * 8;
            bf16x8 af[8], bfr[4];
#pragma unroll
            for (int m = 0; m < 8; ++m)
                af[m] = *reinterpret_cast<const bf16x8*>(&Als[(m * 16 + la) * BK + uo]);
#pragma unroll
            for (int n = 0; n < 4; ++n)
                bfr[n] = *reinterpret_cast<const bf16x8*>(&Bls[(wave * 64 + n * 16 + la) * BK + uo]);
#pragma unroll
            for (int m = 0; m < 8; ++m)
#pragma unroll
                for (int n = 0; n < 4; ++n)
                    acc[m][n] = MF(af[m], bfr[n], acc[m][n]);
        }
        __syncthreads();
    }

    const int rowT = tileM + lh * 4;
    const int colT = tileN + wave * 64;
    unsigned short* outB = (unsigned short*)out;

    const int* mp = nullptr;
    if constexpr (EPI == 0) mp = masks.p[tileN >> 10];
    if constexpr (EPI == 5) mp = masks.p[(tileN >> 10) & 3];
    const float* bp = nullptr;
    const float* bp2 = nullptr;
    if constexpr (EPI == 5) bp2 = bias.p[tileN >> 12];
    else bp = bias.p[tileN >> 10];

#pragma unroll
    for (int n = 0; n < 4; ++n) {
        const int gcol = colT + n * 16 + la;
        float bv, bv2 = 0.f;
        if constexpr (EPI == 5) { bv = biasA[gcol]; bv2 = bp2[gcol & (DM - 1)]; }
        else bv = bp[gcol & (DM - 1)];
#pragma unroll
        for (int m = 0; m < 8; ++m) {
#pragma unroll
            for (int i = 0; i < 4; ++i) {
                const int grow = rowT + m * 16 + i;
                float val = acc[m][n][i] + bv;
                if constexpr (EPI == 0) {
                    val *= (float)mp[grow];
                    outB[(size_t)grow * Nc + gcol] = f2bf(val);
                } else if constexpr (EPI == 1) {
                    outB[(size_t)grow * Nc + gcol] = f2bf(val);
                } else if constexpr (EPI == 2) {
                    val = 0.5f * val * (1.0f + erff(val * 0.70710678118654752f));
                    outB[(size_t)grow * Nc + gcol] = f2bf(val);
                } else if constexpr (EPI == 3) {
                    outB[(size_t)grow * Nc + gcol] = f2bf(val);
                } else { // EPI == 5
                    val = (float)mp[grow] * val + bv2;
                    outB[(size_t)grow * Nc + gcol] = f2bf(val);
                }
            }
        }
    }
}

// ---------------- weight-fusion prep GEMM (R10 16x16 core, strided) ----------------
template <bool TSTORE>
__global__ void gemm_prep(const unsigned short* __restrict__ A0, int lda, int aZoff,
                          const unsigned short* __restrict__ Bt, int ldb,
                          unsigned short* __restrict__ out, int ldc, int cZstride,
                          int K) {
    __shared__ __attribute__((aligned(16))) unsigned short Als[BM * BK];
    __shared__ __attribute__((aligned(16))) unsigned short Bls[BN * BK];
    const unsigned short* A = A0 + (size_t)blockIdx.z * aZoff;
    const int tid = threadIdx.x;
    const int wave = tid >> 6, lane = tid & 63;
    const int2 bxy = swz_xy<0>();
    const int tileM = bxy.y * BM, tileN = bxy.x * BN;
    const int wr = wave >> 1, wc = wave & 1;
    const int la = lane & 15, lh = lane >> 4;

    f32x4 acc[4][4] = {};

    const int sr = tid >> 3;
    const int sb = (tid & 7) * 16;
    const int ssw = (sb ^ ((sr & 7) << 4)) >> 1;
    const unsigned short* aSrcs[4];
    const unsigned short* bSrcs[4];
#pragma unroll
    for (int c = 0; c < 4; ++c) {
        aSrcs[c] = A + (size_t)(tileM + c * 32 + sr) * lda + ssw;
        bSrcs[c] = Bt + (size_t)(tileN + c * 32 + sr) * ldb + ssw;
    }

    for (int k0 = 0; k0 < K; k0 += BK) {
#pragma unroll
        for (int c = 0; c < 4; ++c)
            gload16(aSrcs[c] + k0, &Als[wave * 512 + c * 2048]);
#pragma unroll
        for (int c = 0; c < 4; ++c)
            gload16(bSrcs[c] + k0, &Bls[wave * 512 + c * 2048]);
        __syncthreads();
#pragma unroll
        for (int ks = 0; ks < 2; ++ks) {
            const int uo = ((ks * 4 + lh) ^ (la & 7)) * 8;
            bf16x8 af[4], bfr[4];
#pragma unroll
            for (int m = 0; m < 4; ++m)
                af[m] = *reinterpret_cast<const bf16x8*>(&Als[(wr * 64 + m * 16 + la) * BK + uo]);
#pragma unroll
            for (int n = 0; n < 4; ++n)
                bfr[n] = *reinterpret_cast<const bf16x8*>(&Bls[(wc * 64 + n * 16 + la) * BK + uo]);
#pragma unroll
            for (int m = 0; m < 4; ++m)
#pragma unroll
                for (int n = 0; n < 4; ++n)
                    acc[m][n] = MF(af[m], bfr[n], acc[m][n]);
        }
        __syncthreads();
    }

    const int rowT = tileM + wr * 64 + lh * 4;
    const int colT = tileN + wc * 64;

#pragma unroll
    for (int n = 0; n < 4; ++n) {
        const int gcol = colT + n * 16 + la;
#pragma unroll
        for (int m = 0; m < 4; ++m) {
            if constexpr (TSTORE) {
                const int g0 = rowT + m * 16;
                ushort4 o4;
                o4.x = f2bf(acc[m][n][0]);
                o4.y = f2bf(acc[m][n][1]);
                o4.z = f2bf(acc[m][n][2]);
                o4.w = f2bf(acc[m][n][3]);
                const size_t drow = ((size_t)(gcol >> 10) << 12) +
                                    ((size_t)(g0 >> 10) << 10) + (gcol & 1023);
                *reinterpret_cast<ushort4*>(out + drow * 1024 + (g0 & 1023)) = o4;
            } else {
#pragma unroll
                for (int i = 0; i < 4; ++i) {
                    const int grow = rowT + m * 16 + i;
                    out[(size_t)grow * ldc + (size_t)blockIdx.z * cZstride + gcol] =
                        f2bf(acc[m][n][i]);
                }
            }
        }
    }
}

// ---------------- bias folding ----------------
__global__ void fuse_biasA(Ptr4 bmods, const unsigned short* __restrict__ Btqkv,
                           float* __restrict__ biasA) {
    const int o = blockIdx.x * 4 + (threadIdx.x >> 6);
    const int lane = threadIdx.x & 63;
    const int qk = o >> 12, im = (o >> 10) & 3, j = o & 1023;
    const float* b = bmods.p[im];
    const unsigned short* wrow = Btqkv + ((size_t)(qk << 10) + j) * 1024;
    float s = 0.f;
    for (int t = lane; t < 1024; t += 64) s += b[t] * bf2f(wrow[t]);
#pragma unroll
    for (int off = 32; off >= 1; off >>= 1) s += __shfl_xor(s, off, 64);
    if (lane == 0) biasA[o] = s;
}

__global__ void fuse_biasH(const float* __restrict__ bo, const float* __restrict__ bg1,
                           const unsigned short* __restrict__ Btg1,
                           float* __restrict__ biasH) {
    const int c = blockIdx.x * 4 + (threadIdx.x >> 6);
    const int lane = threadIdx.x & 63;
    const unsigned short* row = Btg1 + (size_t)c * 4096;
    float s = 0.f;
    for (int t = lane; t < 4096; t += 64) s += bo[t & 1023] * bf2f(row[t]);
#pragma unroll
    for (int off = 32; off >= 1; off >>= 1) s += __shfl_xor(s, off, 64);
    if (lane == 0) biasH[c] = s + bg1[c];
}

// ---------------- tiny 4-token attention, fused-QKV layout ----------------
__global__ void attn4F(const unsigned short* __restrict__ qkvF,
                       unsigned short* __restrict__ ctx) {
    const int n = blockIdx.x;
    const int h = threadIdx.x >> 6;
    const int lane = threadIdx.x & 63;
    const size_t base = (size_t)n * 12288 + h * HD + lane * 4;

    float q[4][4], k[4][4], v[4][4];
#pragma unroll
    for (int m = 0; m < 4; ++m) {
        ushort4 uq = *reinterpret_cast<const ushort4*>(&qkvF[base + m * 1024]);
        ushort4 uk = *reinterpret_cast<const ushort4*>(&qkvF[base + m * 1024 + 4096]);
        ushort4 uv = *reinterpret_cast<const ushort4*>(&qkvF[base + m * 1024 + 8192]);
        q[m][0] = bf2f(uq.x); q[m][1] = bf2f(uq.y); q[m][2] = bf2f(uq.z); q[m][3] = bf2f(uq.w);
        k[m][0] = bf2f(uk.x); k[m][1] = bf2f(uk.y); k[m][2] = bf2f(uk.z); k[m][3] = bf2f(uk.w);
        v[m][0] = bf2f(uv.x); v[m][1] = bf2f(uv.y); v[m][2] = bf2f(uv.z); v[m][3] = bf2f(uv.w);
    }

    float s[4][4];
#pragma unroll
    for (int qi = 0; qi < 4; ++qi)
#pragma unroll
        for (int ki = 0; ki < 4; ++ki)
            s[qi][ki] = q[qi][0] * k[ki][0] + q[qi][1] * k[ki][1] +
                        q[qi][2] * k[ki][2] + q[qi][3] * k[ki][3];
#pragma unroll
    for (int off = 32; off >= 1; off >>= 1) {
#pragma unroll
        for (int qi = 0; qi < 4; ++qi)
#pragma unroll
            for (int ki = 0; ki < 4; ++ki)
                s[qi][ki] += __shfl_xor(s[qi][ki], off, 64);
    }

#pragma unroll
    for (int qi = 0; qi < 4; ++qi) {
        float s0 = s[qi][0] * 0.0625f, s1 = s[qi][1] * 0.0625f;
        float s2 = s[qi][2] * 0.0625f, s3 = s[qi][3] * 0.0625f;
        float mx = fmaxf(fmaxf(s0, s1), fmaxf(s2, s3));
        float e0 = __expf(s0 - mx), e1 = __expf(s1 - mx);
        float e2 = __expf(s2 - mx), e3 = __expf(s3 - mx);
        float inv = 1.0f / (e0 + e1 + e2 + e3);
        e0 *= inv; e1 *= inv; e2 *= inv; e3 *= inv;
        ushort4 o;
        o.x = f2bf(e0 * v[0][0] + e1 * v[1][0] + e2 * v[2][0] + e3 * v[3][0]);
        o.y = f2bf(e0 * v[0][1] + e1 * v[1][1] + e2 * v[2][1] + e3 * v[3][1]);
        o.z = f2bf(e0 * v[0][2] + e1 * v[1][2] + e2 * v[2][2] + e3 * v[3][2]);
        o.w = f2bf(e0 * v[0][3] + e1 * v[1][3] + e2 * v[2][3] + e3 * v[3][3]);
        *reinterpret_cast<ushort4*>(&ctx[(size_t)n * 4096 + qi * 1024 + h * HD + lane * 4]) = o;
    }
}

// ---------------- tiny 4-token attention, legacy layout (plan A) ----------------
__global__ void attn4(const unsigned short* __restrict__ qkv,
                      unsigned short* __restrict__ ctx) {
    const int n = blockIdx.x;
    const int h = threadIdx.x >> 6;
    const int lane = threadIdx.x & 63;
    const size_t base = (size_t)n * 4 * 3072 + h * HD + lane * 4;

    float q[4][4], k[4][4], v[4][4];
#pragma unroll
    for (int m = 0; m < 4; ++m) {
        ushort4 uq = *reinterpret_cast<const ushort4*>(&qkv[base + (size_t)m * 3072]);
        ushort4 uk = *reinterpret_cast<const ushort4*>(&qkv[base + (size_t)m * 3072 + 1024]);
        ushort4 uv = *reinterpret_cast<const ushort4*>(&qkv[base + (size_t)m * 3072 + 2048]);
        q[m][0] = bf2f(uq.x); q[m][1] = bf2f(uq.y); q[m][2] = bf2f(uq.z); q[m][3] = bf2f(uq.w);
        k[m][0] = bf2f(uk.x); k[m][1] = bf2f(uk.y); k[m][2] = bf2f(uk.z); k[m][3] = bf2f(uk.w);
        v[m][0] = bf2f(uv.x); v[m][1] = bf2f(uv.y); v[m][2] = bf2f(uv.z); v[m][3] = bf2f(uv.w);
    }

    float s[4][4];
#pragma unroll
    for (int qi = 0; qi < 4; ++qi)
#pragma unroll
        for (int ki = 0; ki < 4; ++ki)
            s[qi][ki] = q[qi][0] * k[ki][0] + q[qi][1] * k[ki][1] +
                        q[qi][2] * k[ki][2] + q[qi][3] * k[ki][3];
#pragma unroll
    for (int off = 32; off >= 1; off >>= 1) {
#pragma unroll
        for (int qi = 0; qi < 4; ++qi)
#pragma unroll
            for (int ki = 0; ki < 4; ++ki)
                s[qi][ki] += __shfl_xor(s[qi][ki], off, 64);
    }

#pragma unroll
    for (int qi = 0; qi < 4; ++qi) {
        float s0 = s[qi][0] * 0.0625f, s1 = s[qi][1] * 0.0625f;
        float s2 = s[qi][2] * 0.0625f, s3 = s[qi][3] * 0.0625f;
        float mx = fmaxf(fmaxf(s0, s1), fmaxf(s2, s3));
        float e0 = __expf(s0 - mx), e1 = __expf(s1 - mx);
        float e2 = __expf(s2 - mx), e3 = __expf(s3 - mx);
        float inv = 1.0f / (e0 + e1 + e2 + e3);
        e0 *= inv; e1 *= inv; e2 *= inv; e3 *= inv;
        ushort4 o;
        o.x = f2bf(e0 * v[0][0] + e1 * v[1][0] + e2 * v[2][0] + e3 * v[3][0]);
        o.y = f2bf(e0 * v[0][1] + e1 * v[1][1] + e2 * v[2][1] + e3 * v[3][1]);
        o.z = f2bf(e0 * v[0][2] + e1 * v[1][2] + e2 * v[2][2] + e3 * v[3][2]);
        o.w = f2bf(e0 * v[0][3] + e1 * v[1][3] + e2 * v[2][3] + e3 * v[3][3]);
        *reinterpret_cast<ushort4*>(&ctx[(size_t)(n * 4 + qi) * 1024 + h * HD + lane * 4]) = o;
    }
}

// ---------------- residual + LayerNorm (bf16 consensus input) ----------------
__global__ void resid_ln(const unsigned short* __restrict__ cons,
                         const float* __restrict__ feat,
                         const float* __restrict__ g, const float* __restrict__ b,
                         float* __restrict__ out) {
    const int row = blockIdx.x;
    const int t = threadIdx.x;
    const size_t base = (size_t)row * DM + t * 4;
    ushort4 c4 = *reinterpret_cast<const ushort4*>(&cons[base]);
    float4 f = *reinterpret_cast<const float4*>(&feat[base]);
    float y0 = bf2f(c4.x) + f.x, y1 = bf2f(c4.y) + f.y;
    float y2 = bf2f(c4.z) + f.z, y3 = bf2f(c4.w) + f.w;
    float sum = y0 + y1 + y2 + y3;
    float sq = y0 * y0 + y1 * y1 + y2 * y2 + y3 * y3;
#pragma unroll
    for (int off = 32; off >= 1; off >>= 1) {
        sum += __shfl_xor(sum, off, 64);
        sq += __shfl_xor(sq, off, 64);
    }
    __shared__ float rs[4], rq[4];
    const int wv = t >> 6, ln = t & 63;
    if (ln == 0) { rs[wv] = sum; rq[wv] = sq; }
    __syncthreads();
    sum = rs[0] + rs[1] + rs[2] + rs[3];
    sq = rq[0] + rq[1] + rq[2] + rq[3];
    const float mu = sum * (1.0f / DM);
    const float var = sq * (1.0f / DM) - mu * mu;
    const float rstd = rsqrtf(var + 1e-5f);
    float4 gg = *reinterpret_cast<const float4*>(&g[t * 4]);
    float4 bb = *reinterpret_cast<const float4*>(&b[t * 4]);
    float4 o;
    o.x = (y0 - mu) * rstd * gg.x + bb.x;
    o.y = (y1 - mu) * rstd * gg.y + bb.y;
    o.z = (y2 - mu) * rstd * gg.z + bb.z;
    o.w = (y3 - mu) * rstd * gg.w + bb.w;
    *reinterpret_cast<float4*>(&out[base]) = o;
}

// ---------------- launch ----------------
extern "C" void kernel_launch(void* const* d_in, const int* in_sizes, int n_in,
                              void* d_out, int out_size, void* d_ws, size_t ws_size,
                              hipStream_t stream) {
    (void)in_sizes; (void)n_in; (void)out_size;
    const float* feat = (const float*)d_in[0];
    const int* am = (const int*)d_in[1];
    const int* dmk = (const int*)d_in[2];
    const int* em = (const int*)d_in[3];
    const int* hmk = (const int*)d_in[4];
    const float* Wa = (const float*)d_in[5];  const float* ba = (const float*)d_in[6];
    const float* Wd = (const float*)d_in[7];  const float* bd = (const float*)d_in[8];
    const float* We = (const float*)d_in[9];  const float* be = (const float*)d_in[10];
    const float* Wh = (const float*)d_in[11]; const float* bh = (const float*)d_in[12];
    const float* Wq = (const float*)d_in[13]; const float* bq = (const float*)d_in[14];
    const float* Wk = (const float*)d_in[15]; const float* bk = (const float*)d_in[16];
    const float* Wv = (const float*)d_in[17]; const float* bv = (const float*)d_in[18];
    const float* Wo = (const float*)d_in[19]; const float* bo = (const float*)d_in[20];
    const float* Wg1 = (const float*)d_in[21]; const float* bg1 = (const float*)d_in[22];
    const float* Wg2 = (const float*)d_in[23]; const float* bg2 = (const float*)d_in[24];
    const float* lng = (const float*)d_in[25]; const float* lnb = (const float*)d_in[26];

    char* ws = (char*)d_ws;
    size_t off = 0;
    auto take = [&](size_t bytes) -> char* {
        char* r = ws + off;
        off = (off + bytes + 255) & ~(size_t)255;
        return r;
    };
    // ---- fixed allocations (~97 MB) ----
    unsigned short* featB = (unsigned short*)take((size_t)NT * DM * 2);
    unsigned short* Btqkv = (unsigned short*)take((size_t)3 * DM * DM * 2);
    unsigned short* Btg1  = (unsigned short*)take((size_t)2 * DM * 4 * DM * 2);
    unsigned short* Btg2  = (unsigned short*)take((size_t)DM * 2 * DM * 2);
    unsigned short* Wcat  = (unsigned short*)take((size_t)4 * DM * DM * 2);
    unsigned short* Wo_bf = (unsigned short*)take((size_t)DM * DM * 2);
    unsigned short* Btf   = (unsigned short*)take((size_t)12 * DM * DM * 2);
    unsigned short* Btm1  = (unsigned short*)take((size_t)8 * DM * DM * 2);
    float* biasA          = (float*)take((size_t)12 * DM * 4);
    float* biasH          = (float*)take((size_t)2 * DM * 4);
    const size_t fixed = off;

    // shared prep
    cvt_f32_to_bf16<<<dim3((NT * DM / 4 + 255) / 256), dim3(256), 0, stream>>>(
        feat, featB, NT * DM / 4);
    auto tl = [&](const float* src, unsigned short* dst, int K, int Nc) {
        transpose_cvt<<<dim3(Nc / 32, K / 32), dim3(256), 0, stream>>>(src, dst, K, Nc);
    };
    tl(Wq, Btqkv, DM, DM);
    tl(Wk, Btqkv + (size_t)DM * DM, DM, DM);
    tl(Wv, Btqkv + (size_t)2 * DM * DM, DM, DM);
    tl(Wg1, Btg1, 4 * DM, 2 * DM);
    tl(Wg2, Btg2, 2 * DM, DM);

    Ptr4 bmods{{ba, bd, be, bh}};
    Ptr4 bqkv{{bq, bk, bv, nullptr}};
    Ptr4 bH{{biasH, biasH + DM, nullptr, nullptr}};
    Ptr4 bg24{{bg2, nullptr, nullptr, nullptr}};
    Mask4 mnull{{nullptr, nullptr, nullptr, nullptr}};

    // ---- plan B sizing: largest T2 that fits ----
    const size_t ctxBytes = (size_t)NT * 4096 * 2;
    const size_t hBytes = (size_t)NT * 2048 * 2 + 512;
    int T2 = 0;
    {
        const int cands[4] = {8192, 4096, 2048, 1024};
        for (int ci = 0; ci < 4; ++ci) {
            int c = cands[ci];
            size_t chunkB = (size_t)c * 24576 + 512;
            size_t regHB = chunkB > hBytes ? chunkB : hBytes;
            if (fixed + ctxBytes + 256 + regHB + 4096 <= ws_size) { T2 = c; break; }
        }
    }

    if (T2 > 0) {
        char* regX = take(ctxBytes);
        size_t chunkB = (size_t)T2 * 24576 + 512;
        char* regH = take(chunkB > hBytes ? chunkB : hBytes);
        unsigned short* ctx = (unsigned short*)regX;    // ctx bf16 [NT][4096]
        unsigned short* cons = (unsigned short*)regX;   // consensus bf16 (aliases ctx)
        unsigned short* h = (unsigned short*)regH;      // gelu-h bf16 [NT][2048]
        unsigned short* qkvF = (unsigned short*)regH;   // qkv chunk bf16 [T2][12288]

        // fused-weight prep
        Ptr4 w4{{Wa, Wd, We, Wh}};
        cvt5_f32_to_bf16<<<dim3(5 * DM * DM / 4 / 256), dim3(256), 0, stream>>>(
            w4, Wo, Wcat, Wo_bf);
        gemm_prep<true><<<dim3(24, 32, 1), dim3(256), 0, stream>>>(
            Wcat, DM, 0, Btqkv, DM, Btf, 0, 0, DM);
        gemm_prep<false><<<dim3(8, 16, 4), dim3(256), 0, stream>>>(
            Btg1, 4 * DM, DM, Wo_bf, DM, Btm1, 4 * DM, DM, DM);
        fuse_biasA<<<dim3(12 * DM / 4), dim3(256), 0, stream>>>(bmods, Btqkv, biasA);
        fuse_biasH<<<dim3(2 * DM / 4), dim3(256), 0, stream>>>(bo, bg1, Btg1, biasH);

        // fused QKV (2-wave high-reuse core, column-sliced XCD) + attention
        for (int t0 = 0; t0 < NT; t0 += T2) {
            Mask4 mk{{am + t0, dmk + t0, em + t0, hmk + t0}};
            gemm_bt2<5, 1><<<dim3(96, T2 / BM), dim3(128), 0, stream>>>(
                featB + (size_t)t0 * DM, Btf, (void*)qkvF, bqkv, mk, biasA,
                T2, 12 * DM, DM);
            attn4F<<<dim3(T2), dim3(256), 0, stream>>>(qkvF, ctx + (size_t)t0 * 4096);
        }
        // MLP1 (fused Wo@Wg1) + GELU (2-wave core): h[NT][2048]
        gemm_bt2<2, 0><<<dim3(16, NT / BM), dim3(128), 0, stream>>>(
            ctx, Btm1, (void*)h, bH, mnull, nullptr, NT, 2 * DM, 4 * DM);
        // MLP2: cons bf16 [NT][1024] (R10 core)
        gemm_bt<3><<<dim3(8, NT / BM), dim3(256), 0, stream>>>(
            h, Btg2, (void*)cons, bg24, mnull, nullptr, NT, DM, 2 * DM);
        // residual + LayerNorm
        resid_ln<<<dim3(NT), dim3(256), 0, stream>>>(cons, feat, lng, lnb, (float*)d_out);
        return;
    }

    // ---- plan A fallback (fully-chunked unfused pipeline, R10 core) ----
    unsigned short* Bt1 = (unsigned short*)take((size_t)4 * DM * DM * 2);
    unsigned short* Bto = (unsigned short*)take((size_t)DM * DM * 2);
    tl(Wa, Bt1, DM, DM);
    tl(Wd, Bt1 + (size_t)DM * DM, DM, DM);
    tl(We, Bt1 + (size_t)2 * DM * DM, DM, DM);
    tl(Wh, Bt1 + (size_t)3 * DM * DM, DM, DM);
    tl(Wo, Bto, DM, DM);

    Ptr4 b1{{ba, bd, be, bh}};
    Ptr4 bo4{{bo, nullptr, nullptr, nullptr}};
    Ptr4 bg14{{bg1, bg1 + DM, nullptr, nullptr}};

    const size_t avail = (ws_size > off) ? (ws_size - off) : 0;
    int T = 2048;
    while (T > 128 && ((size_t)T * 40960 + 4096) > avail) T >>= 1;
    unsigned short* bufA = (unsigned short*)take((size_t)T * 4096 * 2);
    unsigned short* bufB = (unsigned short*)take((size_t)T * 4 * 3072 * 2);
    unsigned short* bufC = (unsigned short*)take((size_t)T * 4 * 1024 * 2);

    const int nch = NT / T;
    for (int c = 0; c < nch; ++c) {
        const int t0 = c * T;
        Mask4 mk{{am + t0, dmk + t0, em + t0, hmk + t0}};
        gemm_bt<0><<<dim3(4 * DM / BN, T / BM), dim3(256), 0, stream>>>(
            featB + (size_t)t0 * DM, Bt1, (void*)bufA, b1, mk, nullptr, T, 4 * DM, DM);
        gemm_bt<1><<<dim3(3 * DM / BN, 4 * T / BM), dim3(256), 0, stream>>>(
            bufA, Btqkv, (void*)bufB, bqkv, mnull, nullptr, 4 * T, 3 * DM, DM);
        attn4<<<dim3(T), dim3(256), 0, stream>>>(bufB, bufC);
        gemm_bt<1><<<dim3(DM / BN, 4 * T / BM), dim3(256), 0, stream>>>(
            bufC, Bto, (void*)bufA, bo4, mnull, nullptr, 4 * T, DM, DM);
        gemm_bt<2><<<dim3(2 * DM / BN, T / BM), dim3(256), 0, stream>>>(
            bufA, Btg1, (void*)bufC, bg14, mnull, nullptr, T, 2 * DM, 4 * DM);
        gemm_bt<3><<<dim3(DM / BN, T / BM), dim3(256), 0, stream>>>(
            bufC, Btg2, (void*)bufB, bg24, mnull, nullptr, T, DM, 2 * DM);
        resid_ln<<<dim3(T), dim3(256), 0, stream>>>(
            bufB, feat + (size_t)t0 * DM, lng, lnb,
            (float*)d_out + (size_t)t0 * DM);
    }
}

// Round 13
// 584.466 us; speedup vs baseline: 1.6907x; 1.2692x over previous
//
#include <hip/hip_runtime.h>
#include <cstdint>
#include <cstddef>

// ---------------- constants ----------------
#define DM   1024          // model dim
#define NT   8192          // B*L tokens
#define HD   256
#define BM 128
#define BN 128
#define BK 64

typedef __attribute__((ext_vector_type(4))) float f32x4;
typedef __attribute__((ext_vector_type(8))) short bf16x8;

#define MF(a_, b_, c_) __builtin_amdgcn_mfma_f32_16x16x32_bf16(a_, b_, c_, 0, 0, 0)

__device__ __forceinline__ unsigned short f2bf(float f) {
    union { float f; uint32_t u; } v; v.f = f;
    return (unsigned short)((v.u + 0x7fffu + ((v.u >> 16) & 1u)) >> 16);
}
__device__ __forceinline__ float bf2f(unsigned short h) {
    union { uint32_t u; float f; } v; v.u = ((uint32_t)h) << 16;
    return v.f;
}

// XCD-aware tile mapping. SWZ=0: row-chunk (A-heavy). SWZ=1: column-slice
// (B-heavy: QKV, B=25MB >> A).
template <int SWZ>
__device__ __forceinline__ int2 swz_xy() {
    int wid = blockIdx.y * gridDim.x + blockIdx.x;
    const int nwg = gridDim.x * gridDim.y;
    int2 r;
    if (SWZ == 1 && (gridDim.x & 7) == 0) {
        const int sx = gridDim.x >> 3;
        const int c = wid & 7;
        const int l = wid >> 3;
        r.x = c * sx + l % sx;
        r.y = l / sx;
        return r;
    }
    if ((nwg & 7) == 0) {
        const int per = nwg >> 3;
        wid = (wid & 7) * per + (wid >> 3);
    }
    r.x = wid % gridDim.x;
    r.y = wid / gridDim.x;
    return r;
}

struct Ptr4 { const float* p[4]; };
struct Mask4 { const int* p[4]; };

// ---------------- prep kernels ----------------
__global__ void cvt_f32_to_bf16(const float* __restrict__ src,
                                unsigned short* __restrict__ dst, int n4) {
    int i = blockIdx.x * blockDim.x + threadIdx.x;
    if (i >= n4) return;
    float4 v = reinterpret_cast<const float4*>(src)[i];
    ushort4 o;
    o.x = f2bf(v.x); o.y = f2bf(v.y); o.z = f2bf(v.z); o.w = f2bf(v.w);
    reinterpret_cast<ushort4*>(dst)[i] = o;
}

__global__ void cvt5_f32_to_bf16(Ptr4 w4, const float* __restrict__ wo,
                                 unsigned short* __restrict__ wcat,
                                 unsigned short* __restrict__ wobf) {
    const int i = blockIdx.x * blockDim.x + threadIdx.x;
    const int w = i >> 18, r = i & 262143;
    const float* src = (w < 4) ? w4.p[w] : wo;
    unsigned short* dst = (w < 4) ? (wcat + ((size_t)w << 20)) : wobf;
    float4 v = reinterpret_cast<const float4*>(src)[r];
    ushort4 o;
    o.x = f2bf(v.x); o.y = f2bf(v.y); o.z = f2bf(v.z); o.w = f2bf(v.w);
    reinterpret_cast<ushort4*>(dst)[r] = o;
}

// src fp32 [K][Nc] row-major  ->  dst bf16 [Nc][K] row-major (transposed)
__global__ void transpose_cvt(const float* __restrict__ src,
                              unsigned short* __restrict__ dst, int K, int Nc) {
    __shared__ float tile[32][33];
    const int n0 = blockIdx.x * 32, k0 = blockIdx.y * 32;
    const int tx = threadIdx.x & 31, ty = threadIdx.x >> 5;
#pragma unroll
    for (int i = 0; i < 4; ++i) {
        int k = ty + i * 8;
        tile[k][tx] = src[(size_t)(k0 + k) * Nc + n0 + tx];
    }
    __syncthreads();
#pragma unroll
    for (int i = 0; i < 4; ++i) {
        int n = ty + i * 8;
        dst[(size_t)(n0 + n) * K + k0 + tx] = f2bf(tile[tx][n]);
    }
}

__device__ __forceinline__ void gload16(const void* g, void* l) {
    __builtin_amdgcn_global_load_lds(
        (const __attribute__((address_space(1))) void*)g,
        (__attribute__((address_space(3))) void*)l, 16, 0, 0);
}

// ---------------- 128x128 GEMM, BK=64 + both-sides XOR swizzle (R10 core) ----------------
// EPI: 0=(acc+bias)*mask->bf16 | 1=acc+bias->bf16 | 2=gelu->bf16
//      3=acc+bias->bf16 (cons)  | 5=mask*(acc+biasA)+bias2->bf16 (QKV)
template <int EPI, int SWZ = 0>
__global__ void gemm_bt(const unsigned short* __restrict__ A,
                        const unsigned short* __restrict__ Bt,
                        void* __restrict__ out, Ptr4 bias, Mask4 masks,
                        const float* __restrict__ biasA,
                        int M, int Nc, int K) {
    __shared__ __attribute__((aligned(16))) unsigned short Als[BM * BK];
    __shared__ __attribute__((aligned(16))) unsigned short Bls[BN * BK];
    const int tid = threadIdx.x;
    const int wave = tid >> 6, lane = tid & 63;
    const int2 bxy = swz_xy<SWZ>();
    const int tileM = bxy.y * BM, tileN = bxy.x * BN;
    const int wr = wave >> 1, wc = wave & 1;
    const int la = lane & 15, lh = lane >> 4;

    f32x4 acc[4][4] = {};

    const int sr = tid >> 3;
    const int sb = (tid & 7) * 16;
    const int ssw = (sb ^ ((sr & 7) << 4)) >> 1;
    const unsigned short* aSrcs[4];
    const unsigned short* bSrcs[4];
#pragma unroll
    for (int c = 0; c < 4; ++c) {
        aSrcs[c] = A + (size_t)(tileM + c * 32 + sr) * K + ssw;
        bSrcs[c] = Bt + (size_t)(tileN + c * 32 + sr) * K + ssw;
    }

    for (int k0 = 0; k0 < K; k0 += BK) {
#pragma unroll
        for (int c = 0; c < 4; ++c)
            gload16(aSrcs[c] + k0, &Als[wave * 512 + c * 2048]);
#pragma unroll
        for (int c = 0; c < 4; ++c)
            gload16(bSrcs[c] + k0, &Bls[wave * 512 + c * 2048]);
        __syncthreads();
#pragma unroll
        for (int ks = 0; ks < 2; ++ks) {
            const int uo = ((ks * 4 + lh) ^ (la & 7)) * 8;
            bf16x8 af[4], bfr[4];
#pragma unroll
            for (int m = 0; m < 4; ++m)
                af[m] = *reinterpret_cast<const bf16x8*>(&Als[(wr * 64 + m * 16 + la) * BK + uo]);
#pragma unroll
            for (int n = 0; n < 4; ++n)
                bfr[n] = *reinterpret_cast<const bf16x8*>(&Bls[(wc * 64 + n * 16 + la) * BK + uo]);
#pragma unroll
            for (int m = 0; m < 4; ++m)
#pragma unroll
                for (int n = 0; n < 4; ++n)
                    acc[m][n] = MF(af[m], bfr[n], acc[m][n]);
        }
        __syncthreads();
    }

    const int rowT = tileM + wr * 64 + lh * 4;
    const int colT = tileN + wc * 64;
    unsigned short* outB = (unsigned short*)out;

    float mv[4][4];
    if constexpr (EPI == 0 || EPI == 5) {
        const int* mp = (EPI == 0) ? masks.p[tileN >> 10] : masks.p[(tileN >> 10) & 3];
#pragma unroll
        for (int m = 0; m < 4; ++m)
#pragma unroll
            for (int i = 0; i < 4; ++i)
                mv[m][i] = (float)mp[rowT + m * 16 + i];
    }
    const float* bp = nullptr;
    const float* bp2 = nullptr;
    if constexpr (EPI == 5) bp2 = bias.p[tileN >> 12];
    else bp = bias.p[tileN >> 10];

#pragma unroll
    for (int n = 0; n < 4; ++n) {
        const int gcol = colT + n * 16 + la;
        float bv, bv2 = 0.f;
        if constexpr (EPI == 5) { bv = biasA[gcol]; bv2 = bp2[gcol & (DM - 1)]; }
        else bv = bp[gcol & (DM - 1)];
#pragma unroll
        for (int m = 0; m < 4; ++m) {
#pragma unroll
            for (int i = 0; i < 4; ++i) {
                const int grow = rowT + m * 16 + i;
                float val = acc[m][n][i] + bv;
                if constexpr (EPI == 0) {
                    val *= mv[m][i];
                    outB[(size_t)grow * Nc + gcol] = f2bf(val);
                } else if constexpr (EPI == 1) {
                    outB[(size_t)grow * Nc + gcol] = f2bf(val);
                } else if constexpr (EPI == 2) {
                    val = 0.5f * val * (1.0f + erff(val * 0.70710678118654752f));
                    outB[(size_t)grow * Nc + gcol] = f2bf(val);
                } else if constexpr (EPI == 3) {
                    outB[(size_t)grow * Nc + gcol] = f2bf(val);
                } else { // EPI == 5
                    val = mv[m][i] * val + bv2;
                    outB[(size_t)grow * Nc + gcol] = f2bf(val);
                }
            }
        }
    }
}

// ---------------- weight-fusion prep GEMM (same 16x16 core, strided) ----------------
template <bool TSTORE>
__global__ void gemm_prep(const unsigned short* __restrict__ A0, int lda, int aZoff,
                          const unsigned short* __restrict__ Bt, int ldb,
                          unsigned short* __restrict__ out, int ldc, int cZstride,
                          int K) {
    __shared__ __attribute__((aligned(16))) unsigned short Als[BM * BK];
    __shared__ __attribute__((aligned(16))) unsigned short Bls[BN * BK];
    const unsigned short* A = A0 + (size_t)blockIdx.z * aZoff;
    const int tid = threadIdx.x;
    const int wave = tid >> 6, lane = tid & 63;
    const int2 bxy = swz_xy<0>();
    const int tileM = bxy.y * BM, tileN = bxy.x * BN;
    const int wr = wave >> 1, wc = wave & 1;
    const int la = lane & 15, lh = lane >> 4;

    f32x4 acc[4][4] = {};

    const int sr = tid >> 3;
    const int sb = (tid & 7) * 16;
    const int ssw = (sb ^ ((sr & 7) << 4)) >> 1;
    const unsigned short* aSrcs[4];
    const unsigned short* bSrcs[4];
#pragma unroll
    for (int c = 0; c < 4; ++c) {
        aSrcs[c] = A + (size_t)(tileM + c * 32 + sr) * lda + ssw;
        bSrcs[c] = Bt + (size_t)(tileN + c * 32 + sr) * ldb + ssw;
    }

    for (int k0 = 0; k0 < K; k0 += BK) {
#pragma unroll
        for (int c = 0; c < 4; ++c)
            gload16(aSrcs[c] + k0, &Als[wave * 512 + c * 2048]);
#pragma unroll
        for (int c = 0; c < 4; ++c)
            gload16(bSrcs[c] + k0, &Bls[wave * 512 + c * 2048]);
        __syncthreads();
#pragma unroll
        for (int ks = 0; ks < 2; ++ks) {
            const int uo = ((ks * 4 + lh) ^ (la & 7)) * 8;
            bf16x8 af[4], bfr[4];
#pragma unroll
            for (int m = 0; m < 4; ++m)
                af[m] = *reinterpret_cast<const bf16x8*>(&Als[(wr * 64 + m * 16 + la) * BK + uo]);
#pragma unroll
            for (int n = 0; n < 4; ++n)
                bfr[n] = *reinterpret_cast<const bf16x8*>(&Bls[(wc * 64 + n * 16 + la) * BK + uo]);
#pragma unroll
            for (int m = 0; m < 4; ++m)
#pragma unroll
                for (int n = 0; n < 4; ++n)
                    acc[m][n] = MF(af[m], bfr[n], acc[m][n]);
        }
        __syncthreads();
    }

    const int rowT = tileM + wr * 64 + lh * 4;
    const int colT = tileN + wc * 64;

#pragma unroll
    for (int n = 0; n < 4; ++n) {
        const int gcol = colT + n * 16 + la;
#pragma unroll
        for (int m = 0; m < 4; ++m) {
            if constexpr (TSTORE) {
                const int g0 = rowT + m * 16;
                ushort4 o4;
                o4.x = f2bf(acc[m][n][0]);
                o4.y = f2bf(acc[m][n][1]);
                o4.z = f2bf(acc[m][n][2]);
                o4.w = f2bf(acc[m][n][3]);
                const size_t drow = ((size_t)(gcol >> 10) << 12) +
                                    ((size_t)(g0 >> 10) << 10) + (gcol & 1023);
                *reinterpret_cast<ushort4*>(out + drow * 1024 + (g0 & 1023)) = o4;
            } else {
#pragma unroll
                for (int i = 0; i < 4; ++i) {
                    const int grow = rowT + m * 16 + i;
                    out[(size_t)grow * ldc + (size_t)blockIdx.z * cZstride + gcol] =
                        f2bf(acc[m][n][i]);
                }
            }
        }
    }
}

// ---------------- bias folding ----------------
__global__ void fuse_biasA(Ptr4 bmods, const unsigned short* __restrict__ Btqkv,
                           float* __restrict__ biasA) {
    const int o = blockIdx.x * 4 + (threadIdx.x >> 6);
    const int lane = threadIdx.x & 63;
    const int qk = o >> 12, im = (o >> 10) & 3, j = o & 1023;
    const float* b = bmods.p[im];
    const unsigned short* wrow = Btqkv + ((size_t)(qk << 10) + j) * 1024;
    float s = 0.f;
    for (int t = lane; t < 1024; t += 64) s += b[t] * bf2f(wrow[t]);
#pragma unroll
    for (int off = 32; off >= 1; off >>= 1) s += __shfl_xor(s, off, 64);
    if (lane == 0) biasA[o] = s;
}

__global__ void fuse_biasH(const float* __restrict__ bo, const float* __restrict__ bg1,
                           const unsigned short* __restrict__ Btg1,
                           float* __restrict__ biasH) {
    const int c = blockIdx.x * 4 + (threadIdx.x >> 6);
    const int lane = threadIdx.x & 63;
    const unsigned short* row = Btg1 + (size_t)c * 4096;
    float s = 0.f;
    for (int t = lane; t < 4096; t += 64) s += bo[t & 1023] * bf2f(row[t]);
#pragma unroll
    for (int off = 32; off >= 1; off >>= 1) s += __shfl_xor(s, off, 64);
    if (lane == 0) biasH[c] = s + bg1[c];
}

// ---------------- tiny 4-token attention, fused-QKV layout ----------------
__global__ void attn4F(const unsigned short* __restrict__ qkvF,
                       unsigned short* __restrict__ ctx) {
    const int n = blockIdx.x;
    const int h = threadIdx.x >> 6;
    const int lane = threadIdx.x & 63;
    const size_t base = (size_t)n * 12288 + h * HD + lane * 4;

    float q[4][4], k[4][4], v[4][4];
#pragma unroll
    for (int m = 0; m < 4; ++m) {
        ushort4 uq = *reinterpret_cast<const ushort4*>(&qkvF[base + m * 1024]);
        ushort4 uk = *reinterpret_cast<const ushort4*>(&qkvF[base + m * 1024 + 4096]);
        ushort4 uv = *reinterpret_cast<const ushort4*>(&qkvF[base + m * 1024 + 8192]);
        q[m][0] = bf2f(uq.x); q[m][1] = bf2f(uq.y); q[m][2] = bf2f(uq.z); q[m][3] = bf2f(uq.w);
        k[m][0] = bf2f(uk.x); k[m][1] = bf2f(uk.y); k[m][2] = bf2f(uk.z); k[m][3] = bf2f(uk.w);
        v[m][0] = bf2f(uv.x); v[m][1] = bf2f(uv.y); v[m][2] = bf2f(uv.z); v[m][3] = bf2f(uv.w);
    }

    float s[4][4];
#pragma unroll
    for (int qi = 0; qi < 4; ++qi)
#pragma unroll
        for (int ki = 0; ki < 4; ++ki)
            s[qi][ki] = q[qi][0] * k[ki][0] + q[qi][1] * k[ki][1] +
                        q[qi][2] * k[ki][2] + q[qi][3] * k[ki][3];
#pragma unroll
    for (int off = 32; off >= 1; off >>= 1) {
#pragma unroll
        for (int qi = 0; qi < 4; ++qi)
#pragma unroll
            for (int ki = 0; ki < 4; ++ki)
                s[qi][ki] += __shfl_xor(s[qi][ki], off, 64);
    }

#pragma unroll
    for (int qi = 0; qi < 4; ++qi) {
        float s0 = s[qi][0] * 0.0625f, s1 = s[qi][1] * 0.0625f;
        float s2 = s[qi][2] * 0.0625f, s3 = s[qi][3] * 0.0625f;
        float mx = fmaxf(fmaxf(s0, s1), fmaxf(s2, s3));
        float e0 = __expf(s0 - mx), e1 = __expf(s1 - mx);
        float e2 = __expf(s2 - mx), e3 = __expf(s3 - mx);
        float inv = 1.0f / (e0 + e1 + e2 + e3);
        e0 *= inv; e1 *= inv; e2 *= inv; e3 *= inv;
        ushort4 o;
        o.x = f2bf(e0 * v[0][0] + e1 * v[1][0] + e2 * v[2][0] + e3 * v[3][0]);
        o.y = f2bf(e0 * v[0][1] + e1 * v[1][1] + e2 * v[2][1] + e3 * v[3][1]);
        o.z = f2bf(e0 * v[0][2] + e1 * v[1][2] + e2 * v[2][2] + e3 * v[3][2]);
        o.w = f2bf(e0 * v[0][3] + e1 * v[1][3] + e2 * v[2][3] + e3 * v[3][3]);
        *reinterpret_cast<ushort4*>(&ctx[(size_t)n * 4096 + qi * 1024 + h * HD + lane * 4]) = o;
    }
}

// ---------------- tiny 4-token attention, legacy layout (plan A) ----------------
__global__ void attn4(const unsigned short* __restrict__ qkv,
                      unsigned short* __restrict__ ctx) {
    const int n = blockIdx.x;
    const int h = threadIdx.x >> 6;
    const int lane = threadIdx.x & 63;
    const size_t base = (size_t)n * 4 * 3072 + h * HD + lane * 4;

    float q[4][4], k[4][4], v[4][4];
#pragma unroll
    for (int m = 0; m < 4; ++m) {
        ushort4 uq = *reinterpret_cast<const ushort4*>(&qkv[base + (size_t)m * 3072]);
        ushort4 uk = *reinterpret_cast<const ushort4*>(&qkv[base + (size_t)m * 3072 + 1024]);
        ushort4 uv = *reinterpret_cast<const ushort4*>(&qkv[base + (size_t)m * 3072 + 2048]);
        q[m][0] = bf2f(uq.x); q[m][1] = bf2f(uq.y); q[m][2] = bf2f(uq.z); q[m][3] = bf2f(uq.w);
        k[m][0] = bf2f(uk.x); k[m][1] = bf2f(uk.y); k[m][2] = bf2f(uk.z); k[m][3] = bf2f(uk.w);
        v[m][0] = bf2f(uv.x); v[m][1] = bf2f(uv.y); v[m][2] = bf2f(uv.z); v[m][3] = bf2f(uv.w);
    }

    float s[4][4];
#pragma unroll
    for (int qi = 0; qi < 4; ++qi)
#pragma unroll
        for (int ki = 0; ki < 4; ++ki)
            s[qi][ki] = q[qi][0] * k[ki][0] + q[qi][1] * k[ki][1] +
                        q[qi][2] * k[ki][2] + q[qi][3] * k[ki][3];
#pragma unroll
    for (int off = 32; off >= 1; off >>= 1) {
#pragma unroll
        for (int qi = 0; qi < 4; ++qi)
#pragma unroll
            for (int ki = 0; ki < 4; ++ki)
                s[qi][ki] += __shfl_xor(s[qi][ki], off, 64);
    }

#pragma unroll
    for (int qi = 0; qi < 4; ++qi) {
        float s0 = s[qi][0] * 0.0625f, s1 = s[qi][1] * 0.0625f;
        float s2 = s[qi][2] * 0.0625f, s3 = s[qi][3] * 0.0625f;
        float mx = fmaxf(fmaxf(s0, s1), fmaxf(s2, s3));
        float e0 = __expf(s0 - mx), e1 = __expf(s1 - mx);
        float e2 = __expf(s2 - mx), e3 = __expf(s3 - mx);
        float inv = 1.0f / (e0 + e1 + e2 + e3);
        e0 *= inv; e1 *= inv; e2 *= inv; e3 *= inv;
        ushort4 o;
        o.x = f2bf(e0 * v[0][0] + e1 * v[1][0] + e2 * v[2][0] + e3 * v[3][0]);
        o.y = f2bf(e0 * v[0][1] + e1 * v[1][1] + e2 * v[2][1] + e3 * v[3][1]);
        o.z = f2bf(e0 * v[0][2] + e1 * v[1][2] + e2 * v[2][2] + e3 * v[3][2]);
        o.w = f2bf(e0 * v[0][3] + e1 * v[1][3] + e2 * v[2][3] + e3 * v[3][3]);
        *reinterpret_cast<ushort4*>(&ctx[(size_t)(n * 4 + qi) * 1024 + h * HD + lane * 4]) = o;
    }
}

// ---------------- residual + LayerNorm (bf16 consensus input) ----------------
__global__ void resid_ln(const unsigned short* __restrict__ cons,
                         const float* __restrict__ feat,
                         const float* __restrict__ g, const float* __restrict__ b,
                         float* __restrict__ out) {
    const int row = blockIdx.x;
    const int t = threadIdx.x;
    const size_t base = (size_t)row * DM + t * 4;
    ushort4 c4 = *reinterpret_cast<const ushort4*>(&cons[base]);
    float4 f = *reinterpret_cast<const float4*>(&feat[base]);
    float y0 = bf2f(c4.x) + f.x, y1 = bf2f(c4.y) + f.y;
    float y2 = bf2f(c4.z) + f.z, y3 = bf2f(c4.w) + f.w;
    float sum = y0 + y1 + y2 + y3;
    float sq = y0 * y0 + y1 * y1 + y2 * y2 + y3 * y3;
#pragma unroll
    for (int off = 32; off >= 1; off >>= 1) {
        sum += __shfl_xor(sum, off, 64);
        sq += __shfl_xor(sq, off, 64);
    }
    __shared__ float rs[4], rq[4];
    const int wv = t >> 6, ln = t & 63;
    if (ln == 0) { rs[wv] = sum; rq[wv] = sq; }
    __syncthreads();
    sum = rs[0] + rs[1] + rs[2] + rs[3];
    sq = rq[0] + rq[1] + rq[2] + rq[3];
    const float mu = sum * (1.0f / DM);
    const float var = sq * (1.0f / DM) - mu * mu;
    const float rstd = rsqrtf(var + 1e-5f);
    float4 gg = *reinterpret_cast<const float4*>(&g[t * 4]);
    float4 bb = *reinterpret_cast<const float4*>(&b[t * 4]);
    float4 o;
    o.x = (y0 - mu) * rstd * gg.x + bb.x;
    o.y = (y1 - mu) * rstd * gg.y + bb.y;
    o.z = (y2 - mu) * rstd * gg.z + bb.z;
    o.w = (y3 - mu) * rstd * gg.w + bb.w;
    *reinterpret_cast<float4*>(&out[base]) = o;
}

// ---------------- launch ----------------
extern "C" void kernel_launch(void* const* d_in, const int* in_sizes, int n_in,
                              void* d_out, int out_size, void* d_ws, size_t ws_size,
                              hipStream_t stream) {
    (void)in_sizes; (void)n_in; (void)out_size;
    const float* feat = (const float*)d_in[0];
    const int* am = (const int*)d_in[1];
    const int* dmk = (const int*)d_in[2];
    const int* em = (const int*)d_in[3];
    const int* hmk = (const int*)d_in[4];
    const float* Wa = (const float*)d_in[5];  const float* ba = (const float*)d_in[6];
    const float* Wd = (const float*)d_in[7];  const float* bd = (const float*)d_in[8];
    const float* We = (const float*)d_in[9];  const float* be = (const float*)d_in[10];
    const float* Wh = (const float*)d_in[11]; const float* bh = (const float*)d_in[12];
    const float* Wq = (const float*)d_in[13]; const float* bq = (const float*)d_in[14];
    const float* Wk = (const float*)d_in[15]; const float* bk = (const float*)d_in[16];
    const float* Wv = (const float*)d_in[17]; const float* bv = (const float*)d_in[18];
    const float* Wo = (const float*)d_in[19]; const float* bo = (const float*)d_in[20];
    const float* Wg1 = (const float*)d_in[21]; const float* bg1 = (const float*)d_in[22];
    const float* Wg2 = (const float*)d_in[23]; const float* bg2 = (const float*)d_in[24];
    const float* lng = (const float*)d_in[25]; const float* lnb = (const float*)d_in[26];

    char* ws = (char*)d_ws;
    size_t off = 0;
    auto take = [&](size_t bytes) -> char* {
        char* r = ws + off;
        off = (off + bytes + 255) & ~(size_t)255;
        return r;
    };
    // ---- fixed allocations (~97 MB) ----
    unsigned short* featB = (unsigned short*)take((size_t)NT * DM * 2);
    unsigned short* Btqkv = (unsigned short*)take((size_t)3 * DM * DM * 2);
    unsigned short* Btg1  = (unsigned short*)take((size_t)2 * DM * 4 * DM * 2);
    unsigned short* Btg2  = (unsigned short*)take((size_t)DM * 2 * DM * 2);
    unsigned short* Wcat  = (unsigned short*)take((size_t)4 * DM * DM * 2);
    unsigned short* Wo_bf = (unsigned short*)take((size_t)DM * DM * 2);
    unsigned short* Btf   = (unsigned short*)take((size_t)12 * DM * DM * 2);
    unsigned short* Btm1  = (unsigned short*)take((size_t)8 * DM * DM * 2);
    float* biasA          = (float*)take((size_t)12 * DM * 4);
    float* biasH          = (float*)take((size_t)2 * DM * 4);
    const size_t fixed = off;

    // shared prep
    cvt_f32_to_bf16<<<dim3((NT * DM / 4 + 255) / 256), dim3(256), 0, stream>>>(
        feat, featB, NT * DM / 4);
    auto tl = [&](const float* src, unsigned short* dst, int K, int Nc) {
        transpose_cvt<<<dim3(Nc / 32, K / 32), dim3(256), 0, stream>>>(src, dst, K, Nc);
    };
    tl(Wq, Btqkv, DM, DM);
    tl(Wk, Btqkv + (size_t)DM * DM, DM, DM);
    tl(Wv, Btqkv + (size_t)2 * DM * DM, DM, DM);
    tl(Wg1, Btg1, 4 * DM, 2 * DM);
    tl(Wg2, Btg2, 2 * DM, DM);

    Ptr4 bmods{{ba, bd, be, bh}};
    Ptr4 bqkv{{bq, bk, bv, nullptr}};
    Ptr4 bH{{biasH, biasH + DM, nullptr, nullptr}};
    Ptr4 bg24{{bg2, nullptr, nullptr, nullptr}};
    Mask4 mnull{{nullptr, nullptr, nullptr, nullptr}};

    // ---- plan B sizing: largest T2 that fits ----
    const size_t ctxBytes = (size_t)NT * 4096 * 2;
    const size_t hBytes = (size_t)NT * 2048 * 2 + 512;
    int T2 = 0;
    {
        const int cands[4] = {8192, 4096, 2048, 1024};
        for (int ci = 0; ci < 4; ++ci) {
            int c = cands[ci];
            size_t chunkB = (size_t)c * 24576 + 512;
            size_t regHB = chunkB > hBytes ? chunkB : hBytes;
            if (fixed + ctxBytes + 256 + regHB + 4096 <= ws_size) { T2 = c; break; }
        }
    }

    if (T2 > 0) {
        char* regX = take(ctxBytes);
        size_t chunkB = (size_t)T2 * 24576 + 512;
        char* regH = take(chunkB > hBytes ? chunkB : hBytes);
        unsigned short* ctx = (unsigned short*)regX;    // ctx bf16 [NT][4096]
        unsigned short* cons = (unsigned short*)regX;   // consensus bf16 (aliases ctx)
        unsigned short* h = (unsigned short*)regH;      // gelu-h bf16 [NT][2048]
        unsigned short* qkvF = (unsigned short*)regH;   // qkv chunk bf16 [T2][12288]

        // fused-weight prep
        Ptr4 w4{{Wa, Wd, We, Wh}};
        cvt5_f32_to_bf16<<<dim3(5 * DM * DM / 4 / 256), dim3(256), 0, stream>>>(
            w4, Wo, Wcat, Wo_bf);
        gemm_prep<true><<<dim3(24, 32, 1), dim3(256), 0, stream>>>(
            Wcat, DM, 0, Btqkv, DM, Btf, 0, 0, DM);
        gemm_prep<false><<<dim3(8, 16, 4), dim3(256), 0, stream>>>(
            Btg1, 4 * DM, DM, Wo_bf, DM, Btm1, 4 * DM, DM, DM);
        fuse_biasA<<<dim3(12 * DM / 4), dim3(256), 0, stream>>>(bmods, Btqkv, biasA);
        fuse_biasH<<<dim3(2 * DM / 4), dim3(256), 0, stream>>>(bo, bg1, Btg1, biasH);

        // fused QKV (column-sliced XCD mapping) + attention
        for (int t0 = 0; t0 < NT; t0 += T2) {
            Mask4 mk{{am + t0, dmk + t0, em + t0, hmk + t0}};
            gemm_bt<5, 1><<<dim3(96, T2 / BM), dim3(256), 0, stream>>>(
                featB + (size_t)t0 * DM, Btf, (void*)qkvF, bqkv, mk, biasA,
                T2, 12 * DM, DM);
            attn4F<<<dim3(T2), dim3(256), 0, stream>>>(qkvF, ctx + (size_t)t0 * 4096);
        }
        // MLP1 (fused Wo@Wg1) + GELU: h[NT][2048]
        gemm_bt<2><<<dim3(16, NT / BM), dim3(256), 0, stream>>>(
            ctx, Btm1, (void*)h, bH, mnull, nullptr, NT, 2 * DM, 4 * DM);
        // MLP2: cons bf16 [NT][1024]
        gemm_bt<3><<<dim3(8, NT / BM), dim3(256), 0, stream>>>(
            h, Btg2, (void*)cons, bg24, mnull, nullptr, NT, DM, 2 * DM);
        // residual + LayerNorm
        resid_ln<<<dim3(NT), dim3(256), 0, stream>>>(cons, feat, lng, lnb, (float*)d_out);
        return;
    }

    // ---- plan A fallback (fully-chunked unfused pipeline) ----
    unsigned short* Bt1 = (unsigned short*)take((size_t)4 * DM * DM * 2);
    unsigned short* Bto = (unsigned short*)take((size_t)DM * DM * 2);
    tl(Wa, Bt1, DM, DM);
    tl(Wd, Bt1 + (size_t)DM * DM, DM, DM);
    tl(We, Bt1 + (size_t)2 * DM * DM, DM, DM);
    tl(Wh, Bt1 + (size_t)3 * DM * DM, DM, DM);
    tl(Wo, Bto, DM, DM);

    Ptr4 b1{{ba, bd, be, bh}};
    Ptr4 bo4{{bo, nullptr, nullptr, nullptr}};
    Ptr4 bg14{{bg1, bg1 + DM, nullptr, nullptr}};

    const size_t avail = (ws_size > off) ? (ws_size - off) : 0;
    int T = 2048;
    while (T > 128 && ((size_t)T * 40960 + 4096) > avail) T >>= 1;
    unsigned short* bufA = (unsigned short*)take((size_t)T * 4096 * 2);
    unsigned short* bufB = (unsigned short*)take((size_t)T * 4 * 3072 * 2);
    unsigned short* bufC = (unsigned short*)take((size_t)T * 4 * 1024 * 2);

    const int nch = NT / T;
    for (int c = 0; c < nch; ++c) {
        const int t0 = c * T;
        Mask4 mk{{am + t0, dmk + t0, em + t0, hmk + t0}};
        gemm_bt<0><<<dim3(4 * DM / BN, T / BM), dim3(256), 0, stream>>>(
            featB + (size_t)t0 * DM, Bt1, (void*)bufA, b1, mk, nullptr, T, 4 * DM, DM);
        gemm_bt<1><<<dim3(3 * DM / BN, 4 * T / BM), dim3(256), 0, stream>>>(
            bufA, Btqkv, (void*)bufB, bqkv, mnull, nullptr, 4 * T, 3 * DM, DM);
        attn4<<<dim3(T), dim3(256), 0, stream>>>(bufB, bufC);
        gemm_bt<1><<<dim3(DM / BN, 4 * T / BM), dim3(256), 0, stream>>>(
            bufC, Bto, (void*)bufA, bo4, mnull, nullptr, 4 * T, DM, DM);
        gemm_bt<2><<<dim3(2 * DM / BN, T / BM), dim3(256), 0, stream>>>(
            bufA, Btg1, (void*)bufC, bg14, mnull, nullptr, T, 2 * DM, 4 * DM);
        gemm_bt<3><<<dim3(DM / BN, T / BM), dim3(256), 0, stream>>>(
            bufC, Btg2, (void*)bufB, bg24, mnull, nullptr, T, DM, 2 * DM);
        resid_ln<<<dim3(T), dim3(256), 0, stream>>>(
            bufB, feat + (size_t)t0 * DM, lng, lnb,
            (float*)d_out + (size_t)t0 * DM);
    }
}